// Round 9
// baseline (343.555 us; speedup 1.0000x reference)
//
#include <hip/hip_runtime.h>
#include <hip/hip_bf16.h>

// FeatureExtractionModel on MI355X — round 9.
// k_emb v5: 2-deep load pipeline, 3x4KB bf16 LDS (convert at stage), XOR-swizzled.
// k_ga v4 : v2 structure + one-time LDS staging of rec_edge frags in p-inner
//           (bank-uniform) layout; all layers read LDS. Small register footprint.

typedef __attribute__((ext_vector_type(8))) short bf16x8;
typedef __attribute__((ext_vector_type(4))) float f32x4;

#define MFMA(a, b, c) __builtin_amdgcn_mfma_f32_16x16x32_bf16((a), (b), (c), 0, 0, 0)

#define WB_REC_OFF   0
#define WB_PEP_OFF   83968
#define WB_EDGE_OFF  167936
#define WB_P_OFF     169984
#define WB_R_OFF     186368
#define WB_V_OFF     219136
#define WB_W0_OFF    251904
#define WB_W1_OFF    256000
#define WB_W2_OFF    258048
#define WB_TOTAL     258560

__device__ __forceinline__ unsigned short f2bf(float x) {
  __hip_bfloat16 h = __float2bfloat16(x);
  return __builtin_bit_cast(unsigned short, h);
}
__device__ __forceinline__ float bf2f(unsigned short u) {
  unsigned int t = ((unsigned int)u) << 16;
  return __builtin_bit_cast(float, t);
}
__device__ __forceinline__ bf16x8 loadBc(const unsigned short* base, int chunk, int lane) {
  return *(const bf16x8*)(base + ((size_t)chunk * 64 + lane) * 8);
}
__device__ __forceinline__ float tanhf_fast(float x) {
  float e = __expf(2.f * x);
  return 1.f - 2.f / (e + 1.f);
}

// ---------------- pack all B-operand fragments to bf16 (inline ESM combine) ----------------
__global__ __launch_bounds__(256) void k_pack(
    const float* __restrict__ Wresm, const float* __restrict__ Wpesm,
    const float* __restrict__ Wre, const float* __restrict__ Wpe,
    const float* __restrict__ Wedge, const float* __restrict__ Wp,
    const float* __restrict__ Wr, const float* __restrict__ Wv,
    const float* __restrict__ W0, const float* __restrict__ W1,
    const float* __restrict__ W2, unsigned short* __restrict__ WB) {
  const int t = blockIdx.x * 256 + threadIdx.x;
  if (t >= WB_TOTAL) return;
  float v = 0.f;
  if (t < WB_EDGE_OFF) {
    bool isPep = (t >= WB_PEP_OFF);
    int u = isPep ? (t - WB_PEP_OFF) : t;
    int j = u & 7, lane = (u >> 3) & 63, n = (u >> 9) & 3, kc = u >> 11;
    int k = kc * 32 + ((lane >> 4) << 3) + j;
    int col = n * 16 + (lane & 15);
    if (kc < 40) {
      const float* wemb = isPep ? (Wpe + col * 91 + 27) : (Wre + col * 85 + 21);
      const float* wesm = isPep ? Wpesm : Wresm;
      float s = 0.f;
#pragma unroll 8
      for (int e = 0; e < 64; ++e) s += wemb[e] * wesm[e * 1280 + k];
      v = s;
    } else {
      int kl = k - 1280;
      if (isPep) v = (kl < 27) ? Wpe[col * 91 + kl] : 0.f;
      else       v = (kl < 21) ? Wre[col * 85 + kl] : 0.f;
    }
  } else if (t < WB_P_OFF) {
    int u = t - WB_EDGE_OFF;
    int j = u & 7, lane = (u >> 3) & 63, n = (u >> 9) & 3;
    v = Wedge[(n * 16 + (lane & 15)) * 32 + ((lane >> 4) << 3) + j];
  } else if (t < WB_R_OFF) {
    int u = t - WB_P_OFF;
    int l = u >> 12, w = u & 4095;
    int j = w & 7, lane = (w >> 3) & 63, n = (w >> 9) & 3, kc = w >> 11;
    int o = kc * 32 + ((lane >> 4) << 3) + j;
    int d = n * 16 + (lane & 15);
    v = Wp[l * 4096 + d * 64 + o];
  } else if (t < WB_V_OFF) {
    int u = t - WB_R_OFF;
    int l = u >> 13, w = u & 8191;
    int j = w & 7, lane = (w >> 3) & 63, c = (w >> 9) & 15;
    int kc = c >> 3, n = c & 7;
    int o = kc * 32 + ((lane >> 4) << 3) + j;
    int k = n * 16 + (lane & 15);
    v = Wr[l * 8192 + o * 128 + k];
  } else if (t < WB_W0_OFF) {
    int u = t - WB_V_OFF;
    int l = u >> 13, w = u & 8191;
    int j = w & 7, lane = (w >> 3) & 63, n = (w >> 9) & 3, kc = w >> 11;
    int k = kc * 32 + ((lane >> 4) << 3) + j;
    int d = n * 16 + (lane & 15);
    v = Wv[l * 8192 + d * 128 + k];
  } else if (t < WB_W1_OFF) {
    int u = t - WB_W0_OFF;
    int j = u & 7, lane = (u >> 3) & 63, c = u >> 9;
    int kc = c >> 2, n = c & 3;
    v = W0[(n * 16 + (lane & 15)) * 64 + kc * 32 + ((lane >> 4) << 3) + j];
  } else if (t < WB_W2_OFF) {
    int u = t - WB_W1_OFF;
    int j = u & 7, lane = (u >> 3) & 63, c = u >> 9;
    int kc = c >> 1, n = c & 1;
    v = W1[(n * 16 + (lane & 15)) * 64 + kc * 32 + ((lane >> 4) << 3) + j];
  } else {
    int u = t - WB_W2_OFF;
    int j = u & 7, lane = (u >> 3) & 63;
    v = W2[(lane & 15) * 32 + ((lane >> 4) << 3) + j];
  }
  WB[t] = f2bf(v);
}

// ---------------- k_emb v5: 16 rows per single-wave block, 2-deep pipeline ----------------
// rec tiles: bid in [0,5120); pep tiles: [5120,5632)
__global__ __launch_bounds__(64) void k_emb(
    const float* __restrict__ rec_feat, const float* __restrict__ edge_feat,
    const float* __restrict__ pep_feat, const unsigned short* __restrict__ WB,
    const float* __restrict__ rec_g, const float* __restrict__ rec_b,
    const float* __restrict__ pep_g, const float* __restrict__ pep_b,
    unsigned short* __restrict__ rec_edge, unsigned short* __restrict__ pep_out) {
  __shared__ unsigned short stg[3][16][128];  // 12 KB: 3 bufs x 16 rows x 128 bf16, swizzled
  const int bid = blockIdx.x;
  const int lane = threadIdx.x;
  const int quad = lane >> 4, lr = lane & 15;
  const bool isPep = (bid >= 5120);
  const int brow = (isPep ? bid - 5120 : bid) * 16;
  const float* __restrict__ src = isPep ? pep_feat : rec_feat;
  const int rowlen = isPep ? 1307 : 1322;
  const int head = isPep ? 27 : 42;
  const unsigned short* WBb = WB + (isPep ? WB_PEP_OFF : WB_REC_OFF);

  const f32x4 fz = {0.f, 0.f, 0.f, 0.f};
  f32x4 acc[4] = {fz, fz, fz, fz};

  unsigned int ldu[2][16];  // 2 in-flight groups, bf16-packed (static indices only)

  auto loadg = [&](int g, int s) {
#pragma unroll
    for (int i = 0; i < 16; ++i) {
      const float* p = src + (size_t)(brow + i) * rowlen + head + g * 128 + lane * 2;
      float x0, x1;
      if (!isPep) { const float2 v = *(const float2*)p; x0 = v.x; x1 = v.y; }
      else { x0 = p[0]; x1 = p[1]; }
      ldu[s][i] = (unsigned)f2bf(x0) | ((unsigned)f2bf(x1) << 16);
    }
  };
  // row i, lane l holds elements 2l,2l+1 -> unit u=l>>2 stored at u^(i&7)
  auto writeg = [&](int b, int s) {
#pragma unroll
    for (int i = 0; i < 16; ++i)
      *(unsigned*)((char*)&stg[b][i][0] +
                   ((((lane >> 2) ^ (i & 7)) << 4) | ((lane & 3) << 2))) = ldu[s][i];
  };
  // frag: elements kc*32+quad*8 .. +7 of row lr = unit kc*4+quad at ^(lr&7)
  auto frag = [&](int b, int kc) -> bf16x8 {
    return *(const bf16x8*)((const char*)&stg[b][lr][0] +
                            ((((kc << 2) | quad) ^ (lr & 7)) << 4));
  };

  loadg(0, 0); writeg(0, 0); loadg(1, 1);
#pragma unroll
  for (int g = 0; g < 10; ++g) {
    if (g < 8) loadg(g + 2, g & 1);  // 2 groups ahead
#pragma unroll
    for (int kc = 0; kc < 4; ++kc) {
      const bf16x8 a = frag(g % 3, kc);
#pragma unroll
      for (int n = 0; n < 4; ++n)
        acc[n] = MFMA(a, loadBc(WBb, g * 16 + kc * 4 + n, lane), acc[n]);
    }
    if (g < 9) writeg((g + 1) % 3, (g + 1) & 1);
  }
  {  // head chunk kc=40 (B zero-padded past real head cols)
    const float* p = src + (size_t)(brow + lr) * rowlen + quad * 8;
    bf16x8 a;
    if (!isPep) {
#pragma unroll
      for (int m = 0; m < 4; ++m) {
        const float2 v = *(const float2*)(p + 2 * m);
        a[2 * m] = (short)f2bf(v.x); a[2 * m + 1] = (short)f2bf(v.y);
      }
    } else {
#pragma unroll
      for (int j = 0; j < 8; ++j) a[j] = (short)f2bf(p[j]);
    }
#pragma unroll
    for (int n = 0; n < 4; ++n)
      acc[n] = MFMA(a, loadBc(WBb, 160 + n, lane), acc[n]);
  }

  // LN stats
  float s[4], sq[4];
#pragma unroll
  for (int i = 0; i < 4; ++i) {
    s[i] = acc[0][i] + acc[1][i] + acc[2][i] + acc[3][i];
    sq[i] = acc[0][i] * acc[0][i] + acc[1][i] * acc[1][i] +
            acc[2][i] * acc[2][i] + acc[3][i] * acc[3][i];
  }
#pragma unroll
  for (int msk = 1; msk < 16; msk <<= 1) {
#pragma unroll
    for (int i = 0; i < 4; ++i) {
      s[i] += __shfl_xor(s[i], msk);
      sq[i] += __shfl_xor(sq[i], msk);
    }
  }
  const float* gp = isPep ? pep_g : rec_g;
  const float* bp = isPep ? pep_b : rec_b;
  float gv[4], bvl[4];
#pragma unroll
  for (int n = 0; n < 4; ++n) { gv[n] = gp[lr + 16 * n]; bvl[n] = bp[lr + 16 * n]; }

  if (!isPep) {
    f32x4 acce[4] = {fz, fz, fz, fz};
    {
      const float* p = edge_feat + (size_t)(brow + lr) * 32 + quad * 8;
      const float4 f0 = *(const float4*)(p);
      const float4 f1 = *(const float4*)(p + 4);
      bf16x8 a;
#pragma unroll
      for (int j = 0; j < 4; ++j) { a[j] = (short)f2bf(f0[j]); a[4 + j] = (short)f2bf(f1[j]); }
#pragma unroll
      for (int n = 0; n < 4; ++n) acce[n] = MFMA(a, loadBc(WB + WB_EDGE_OFF, n, lane), acce[n]);
    }
#pragma unroll
    for (int i = 0; i < 4; ++i) {
      const float mean = s[i] * (1.f / 64.f);
      const float var = sq[i] * (1.f / 64.f) - mean * mean;
      const float rstd = rsqrtf(var + 1e-5f);
      unsigned short* dst = rec_edge + (size_t)(brow + quad * 4 + i) * 128;
#pragma unroll
      for (int n = 0; n < 4; ++n) {
        dst[lr + 16 * n] = f2bf((acc[n][i] - mean) * rstd * gv[n] + bvl[n]);
        dst[64 + lr + 16 * n] = f2bf(acce[n][i]);
      }
    }
  } else {
#pragma unroll
    for (int i = 0; i < 4; ++i) {
      const float mean = s[i] * (1.f / 64.f);
      const float var = sq[i] * (1.f / 64.f) - mean * mean;
      const float rstd = rsqrtf(var + 1e-5f);
      unsigned short* dst = pep_out + (size_t)(brow + quad * 4 + i) * 64;
#pragma unroll
      for (int n = 0; n < 4; ++n)
        dst[lr + 16 * n] = f2bf((acc[n][i] - mean) * rstd * gv[n] + bvl[n]);
    }
  }
}

// ---------------- k_ga v4: one-time LDS staging of rec_edge frags (p-inner layout) ----------------
__global__ __launch_bounds__(64) void k_ga(
    const unsigned short* __restrict__ rec_edge, const unsigned short* __restrict__ pep_bf,
    const unsigned short* __restrict__ WB,
    const float* __restrict__ ga_bp, const float* __restrict__ ga_bv,
    const float* __restrict__ pool_g, const float* __restrict__ pool_b,
    float* __restrict__ dbuf, float* __restrict__ logitsT) {
  __shared__ unsigned short rf_s[20480];  // 40KB: [10r][16c][16p] 16B units, p-inner (bank-uniform)
  __shared__ unsigned short pep_s[1024];
  __shared__ unsigned short q_s[1024];
  __shared__ unsigned short zs[2048];
  __shared__ float bias_s[512];

  const int lane = threadIdx.x;
  const int quad = lane >> 4, lr = lane & 15;
  const int swz = lr & 7;
  const int pbase = blockIdx.x * 16;
  const f32x4 fz = {0.f, 0.f, 0.f, 0.f};

#pragma unroll
  for (int i = 0; i < 4; ++i) {
    int f = lane + 64 * i;
    bias_s[f] = ga_bp[f];
    bias_s[256 + f] = ga_bv[f];
  }
#pragma unroll
  for (int i = 0; i < 2; ++i) {
    const int G = lane + 64 * i;
    const int p = G >> 3, gg = G & 7;
    const bf16x8 v = *(const bf16x8*)(pep_bf + (size_t)(pbase + p) * 64 + gg * 8);
    *(bf16x8*)(pep_s + p * 64 + ((gg ^ (p & 7)) << 3)) = v;
  }
  // stage rec_edge frags once: lane (quad,lr) gathers row pbase+lr, chunk quad+4kc, all r
  const unsigned short* reb = rec_edge + (size_t)(pbase + lr) * 1280 + quad * 8;
#pragma unroll
  for (int r = 0; r < 10; ++r)
#pragma unroll
    for (int kc = 0; kc < 4; ++kc)
      *(bf16x8*)(rf_s + ((r * 16 + quad + 4 * kc) * 16 + lr) * 8) =
          *(const bf16x8*)(reb + r * 128 + kc * 32);
  auto rfrag = [&](int r, int kc) -> bf16x8 {
    return *(const bf16x8*)(rf_s + ((r * 16 + quad + 4 * kc) * 16 + lr) * 8);
  };

  auto bwrite = [&](unsigned short* buf, int p, int col, unsigned short val) {
    buf[p * 64 + ((((col >> 3)) ^ (p & 7)) << 3) + (col & 7)] = val;
  };
  auto bfrag = [&](const unsigned short* buf, int kc) -> bf16x8 {
    return *(const bf16x8*)(buf + lr * 64 + ((((kc << 2) + quad) ^ swz) << 3));
  };

  f32x4 pcur[4];
  for (int l = 0; l < 4; ++l) {
    const unsigned short* WBp = WB + WB_P_OFF + l * 4096;
    const unsigned short* WBr = WB + WB_R_OFF + l * 8192;
    const unsigned short* WBv = WB + WB_V_OFF + l * 8192;
    // q = pep @ Wp^T + bp
    f32x4 qa[4] = {fz, fz, fz, fz};
#pragma unroll
    for (int kc = 0; kc < 2; ++kc) {
      bf16x8 a = bfrag(pep_s, kc);
#pragma unroll
      for (int n = 0; n < 4; ++n) qa[n] = MFMA(a, loadBc(WBp, kc * 4 + n, lane), qa[n]);
    }
#pragma unroll
    for (int n = 0; n < 4; ++n) {
      const float bpv = bias_s[l * 64 + lr + 16 * n];
#pragma unroll
      for (int i = 0; i < 4; ++i) qa[n][i] += bpv;
    }
#pragma unroll
    for (int n = 0; n < 4; ++n)
#pragma unroll
      for (int i = 0; i < 4; ++i)
        bwrite(q_s, quad * 4 + i, lr + 16 * n, f2bf(qa[n][i]));
    const bf16x8 aq0 = bfrag(q_s, 0), aq1 = bfrag(q_s, 1);
    // z = Wr^T q  [16 p x 128 k] -> zs (bf16, swizzled)
    f32x4 za[8] = {fz, fz, fz, fz, fz, fz, fz, fz};
#pragma unroll
    for (int n = 0; n < 8; ++n) za[n] = MFMA(aq0, loadBc(WBr, n, lane), za[n]);
#pragma unroll
    for (int n = 0; n < 8; ++n) za[n] = MFMA(aq1, loadBc(WBr, 8 + n, lane), za[n]);
#pragma unroll
    for (int n = 0; n < 8; ++n)
#pragma unroll
      for (int i = 0; i < 4; ++i) {
        const int p = quad * 4 + i, k = 16 * n + lr;
        zs[p * 128 + ((((k >> 3) ^ (p & 7)) << 3) | (k & 7))] = f2bf(za[n][i]);
      }
    float zf[4][8];
#pragma unroll
    for (int kc = 0; kc < 4; ++kc) {
      const bf16x8 z8 = *(const bf16x8*)(zs + lr * 128 + (((quad + 4 * kc) ^ swz) << 3));
#pragma unroll
      for (int j = 0; j < 8; ++j) zf[kc][j] = bf2f((unsigned short)z8[j]);
    }
    // logits from LDS-resident fragments
    float lg[10];
#pragma unroll
    for (int r = 0; r < 10; ++r) {
      float part = 0.f;
#pragma unroll
      for (int kc = 0; kc < 4; ++kc) {
        const bf16x8 rf = rfrag(r, kc);
#pragma unroll
        for (int j = 0; j < 8; ++j) part += bf2f((unsigned short)rf[j]) * zf[kc][j];
      }
      part += __shfl_xor(part, 16);
      part += __shfl_xor(part, 32);
      lg[r] = part * 0.125f;
    }
    float mx = lg[0];
#pragma unroll
    for (int r = 1; r < 10; ++r) mx = fmaxf(mx, lg[r]);
    float ssum = 0.f;
#pragma unroll
    for (int r = 0; r < 10; ++r) { lg[r] = __expf(lg[r] - mx); ssum += lg[r]; }
    const float inv = 1.f / ssum;
#pragma unroll
    for (int r = 0; r < 10; ++r) lg[r] *= inv;
    // ws = sum_r a[r] * re[p][r]
    float wsacc[4][8] = {};
#pragma unroll
    for (int r = 0; r < 10; ++r) {
#pragma unroll
      for (int kc = 0; kc < 4; ++kc) {
        const bf16x8 rf = rfrag(r, kc);
#pragma unroll
        for (int j = 0; j < 8; ++j)
          wsacc[kc][j] += lg[r] * bf2f((unsigned short)rf[j]);
      }
    }
    bf16x8 wf[4];
#pragma unroll
    for (int kc = 0; kc < 4; ++kc)
#pragma unroll
      for (int j = 0; j < 8; ++j) wf[kc][j] = (short)f2bf(wsacc[kc][j]);
    // out = ws @ Wv^T ; pep_new = q + out + bv
    f32x4 oa[4] = {fz, fz, fz, fz};
#pragma unroll
    for (int kc = 0; kc < 4; ++kc)
#pragma unroll
      for (int n = 0; n < 4; ++n) oa[n] = MFMA(wf[kc], loadBc(WBv, kc * 4 + n, lane), oa[n]);
#pragma unroll
    for (int n = 0; n < 4; ++n) {
      const float bvv = bias_s[256 + l * 64 + lr + 16 * n];
#pragma unroll
      for (int i = 0; i < 4; ++i) pcur[n][i] = qa[n][i] + oa[n][i] + bvv;
    }
#pragma unroll
    for (int n = 0; n < 4; ++n)
#pragma unroll
      for (int i = 0; i < 4; ++i)
        bwrite(pep_s, quad * 4 + i, lr + 16 * n, f2bf(pcur[n][i]));
  }

  // ---- pooling head ----
  {
    float s[4], sq[4];
#pragma unroll
    for (int i = 0; i < 4; ++i) {
      s[i] = pcur[0][i] + pcur[1][i] + pcur[2][i] + pcur[3][i];
      sq[i] = pcur[0][i] * pcur[0][i] + pcur[1][i] * pcur[1][i] +
              pcur[2][i] * pcur[2][i] + pcur[3][i] * pcur[3][i];
    }
#pragma unroll
    for (int msk = 1; msk < 16; msk <<= 1) {
#pragma unroll
      for (int i = 0; i < 4; ++i) {
        s[i] += __shfl_xor(s[i], msk);
        sq[i] += __shfl_xor(sq[i], msk);
      }
    }
    float gv[4], bv2[4];
#pragma unroll
    for (int n = 0; n < 4; ++n) { gv[n] = pool_g[lr + 16 * n]; bv2[n] = pool_b[lr + 16 * n]; }
    f32x4 d[4];
#pragma unroll
    for (int i = 0; i < 4; ++i) {
      const float mean = s[i] * (1.f / 64.f);
      const float var = sq[i] * (1.f / 64.f) - mean * mean;
      const float rstd = rsqrtf(var + 1e-5f);
#pragma unroll
      for (int n = 0; n < 4; ++n) d[n][i] = (pcur[n][i] - mean) * rstd * gv[n] + bv2[n];
    }
    float* zf32 = (float*)zs;
#pragma unroll
    for (int n = 0; n < 4; ++n)
#pragma unroll
      for (int i = 0; i < 4; ++i)
        zf32[(quad * 4 + i) * 64 + lr + 16 * n] = d[n][i];
#pragma unroll
    for (int i = 0; i < 4; ++i) {
      const float4 v = *(const float4*)(&zf32[i * 256 + lane * 4]);
      *(float4*)(dbuf + (size_t)pbase * 64 + i * 256 + lane * 4) = v;
    }
#pragma unroll
    for (int n = 0; n < 4; ++n)
#pragma unroll
      for (int i = 0; i < 4; ++i)
        bwrite(q_s, quad * 4 + i, lr + 16 * n, f2bf(d[n][i]));
    const bf16x8 ad0 = bfrag(q_s, 0), ad1 = bfrag(q_s, 1);
    f32x4 h0[4] = {fz, fz, fz, fz};
#pragma unroll
    for (int n = 0; n < 4; ++n) {
      h0[n] = MFMA(ad0, loadBc(WB + WB_W0_OFF, n, lane), h0[n]);
      h0[n] = MFMA(ad1, loadBc(WB + WB_W0_OFF, 4 + n, lane), h0[n]);
    }
#pragma unroll
    for (int n = 0; n < 4; ++n)
#pragma unroll
      for (int i = 0; i < 4; ++i)
        bwrite(q_s, quad * 4 + i, lr + 16 * n, f2bf(tanhf_fast(h0[n][i])));
    const bf16x8 ah00 = bfrag(q_s, 0), ah01 = bfrag(q_s, 1);
    f32x4 h1[2] = {fz, fz};
#pragma unroll
    for (int n = 0; n < 2; ++n) {
      h1[n] = MFMA(ah00, loadBc(WB + WB_W1_OFF, n, lane), h1[n]);
      h1[n] = MFMA(ah01, loadBc(WB + WB_W1_OFF, 2 + n, lane), h1[n]);
    }
#pragma unroll
    for (int n = 0; n < 2; ++n)
#pragma unroll
      for (int i = 0; i < 4; ++i)
        bwrite(q_s, quad * 4 + i, lr + 16 * n, f2bf(tanhf_fast(h1[n][i])));
    const bf16x8 ah1 = bfrag(q_s, 0);
    f32x4 lac = MFMA(ah1, loadBc(WB + WB_W2_OFF, 0, lane), fz);
    const int b = pbase >> 11, sx0 = pbase & 2047;
#pragma unroll
    for (int i = 0; i < 4; ++i)
      logitsT[(size_t)(b * 16 + lr) * 2048 + sx0 + quad * 4 + i] = lac[i];
  }
}

// ---------------- pool2: 256 blocks, redundant softmax stats + partials ----------------
__global__ __launch_bounds__(256) void k_pool2(
    const float* __restrict__ logitsT, const float* __restrict__ dbuf,
    float* __restrict__ attp) {
  __shared__ float sh[2048];
  __shared__ float red[8];
  __shared__ float part[16][64];
  const int blk = blockIdx.x;
  const int bh = blk >> 2, q = blk & 3;
  const int b = bh >> 4;
  const int tid = threadIdx.x, lane = tid & 63, wid = tid >> 6;
  const float* lrow = logitsT + (size_t)bh * 2048;

  float m = -1e30f;
  for (int sx = tid; sx < 2048; sx += 256) {
    float v = lrow[sx];
    sh[sx] = v;
    m = fmaxf(m, v);
  }
#pragma unroll
  for (int msk = 1; msk < 64; msk <<= 1) m = fmaxf(m, __shfl_xor(m, msk));
  if (lane == 0) red[wid] = m;
  __syncthreads();
  m = fmaxf(fmaxf(red[0], red[1]), fmaxf(red[2], red[3]));

  float s1 = 0.f;
  for (int sx = tid; sx < 2048; sx += 256) {
    float e = __expf(sh[sx] - m);
    sh[sx] = e;
    s1 += e;
  }
#pragma unroll
  for (int msk = 1; msk < 64; msk <<= 1) s1 += __shfl_xor(s1, msk);
  __syncthreads();
  if (lane == 0) red[4 + wid] = s1;
  __syncthreads();
  s1 = red[4] + red[5] + red[6] + red[7];
  const float invS1 = 1.f / s1;

  float s2 = 0.f;
  for (int sx = tid; sx < 2048; sx += 256) {
    float e2 = __expf((sh[sx] - 1.f) * invS1);
    sh[sx] = e2;
    s2 += e2;
  }
#pragma unroll
  for (int msk = 1; msk < 64; msk <<= 1) s2 += __shfl_xor(s2, msk);
  __syncthreads();
  if (lane == 0) red[wid] = s2;
  __syncthreads();
  s2 = red[0] + red[1] + red[2] + red[3];
  const float invS2 = 1.f / s2;

  const int d16 = tid & 15, sxg = tid >> 4;
  float4 a4 = {0.f, 0.f, 0.f, 0.f};
  const float* db = dbuf + (size_t)b * 2048 * 64 + d16 * 4;
#pragma unroll 4
  for (int sx = q * 512 + sxg; sx < (q + 1) * 512; sx += 16) {
    const float w = sh[sx];
    const float4 v = *(const float4*)(db + (size_t)sx * 64);
    a4.x += w * v.x; a4.y += w * v.y; a4.z += w * v.z; a4.w += w * v.w;
  }
  *(float4*)(&part[sxg][d16 * 4]) = a4;
  __syncthreads();
  if (tid < 64) {
    float s = 0.f;
#pragma unroll
    for (int g2 = 0; g2 < 16; ++g2) s += part[g2][tid];
    attp[(size_t)(bh * 4 + q) * 64 + tid] = s * invS2;
  }
}

// ---------------- final: reduce partials, mean over heads, project ----------------
__global__ __launch_bounds__(256) void k_final(
    const float* __restrict__ attp, const float* __restrict__ W,
    const float* __restrict__ bias, float* __restrict__ out) {
  __shared__ float pooled[4][64];
  const int tid = threadIdx.x;
  {
    const int b = tid >> 6, d = tid & 63;
    float s = 0.f;
#pragma unroll
    for (int hq = 0; hq < 64; ++hq) s += attp[((size_t)b * 64 + hq) * 64 + d];
    pooled[b][d] = s * (1.f / 16.f);
  }
  __syncthreads();
  if (tid < 128) {
    const int b = tid >> 5, j = tid & 31;
    float s = bias[j];
#pragma unroll
    for (int d2 = 0; d2 < 64; ++d2) s += pooled[b][d2] * W[j * 64 + d2];
    out[b * 32 + j] = s;
  }
}

extern "C" void kernel_launch(void* const* d_in, const int* in_sizes, int n_in,
                              void* d_out, int out_size, void* d_ws, size_t ws_size,
                              hipStream_t stream) {
  const float* pep_feat = (const float*)d_in[0];
  const float* rec_feat = (const float*)d_in[1];
  const float* edge_feat = (const float*)d_in[2];
  const float* W_rec_esm = (const float*)d_in[3];
  const float* W_pep_esm = (const float*)d_in[4];
  const float* W_pep_emb = (const float*)d_in[5];
  const float* W_rec_emb = (const float*)d_in[6];
  const float* W_edge_emb = (const float*)d_in[7];
  const float* pep_ln_g = (const float*)d_in[8];
  const float* pep_ln_b = (const float*)d_in[9];
  const float* rec_ln_g = (const float*)d_in[10];
  const float* rec_ln_b = (const float*)d_in[11];
  const float* ga_Wp = (const float*)d_in[12];
  const float* ga_bp = (const float*)d_in[13];
  const float* ga_Wr = (const float*)d_in[14];
  const float* ga_br = (const float*)d_in[15];
  const float* ga_Wv = (const float*)d_in[16];
  const float* ga_bv = (const float*)d_in[17];
  const float* pool_ln_g = (const float*)d_in[18];
  const float* pool_ln_b = (const float*)d_in[19];
  const float* pool_W0 = (const float*)d_in[20];
  const float* pool_W1 = (const float*)d_in[21];
  const float* pool_W2 = (const float*)d_in[22];
  const float* mlp_W = (const float*)d_in[23];
  const float* mlp_b = (const float*)d_in[24];
  float* out = (float*)d_out;
  (void)ga_br;  // softmax-invariant, algebraically dropped
  (void)ws_size; (void)in_sizes; (void)n_in; (void)out_size;

  char* ws = (char*)d_ws;
  unsigned short* WB = (unsigned short*)(ws);
  unsigned short* rec_edge = (unsigned short*)(ws + 524288);
  unsigned short* pep_bf = (unsigned short*)(ws + 21495808);
  float* dbuf = (float*)(ws + 22544384);
  float* logitsT = (float*)(ws + 24641536);
  float* attp = (float*)(ws + 25165824);

  k_pack<<<1010, 256, 0, stream>>>(W_rec_esm, W_pep_esm, W_rec_emb, W_pep_emb,
                                   W_edge_emb, ga_Wp, ga_Wr, ga_Wv,
                                   pool_W0, pool_W1, pool_W2, WB);
  k_emb<<<5632, 64, 0, stream>>>(rec_feat, edge_feat, pep_feat, WB,
                                 rec_ln_g, rec_ln_b, pep_ln_g, pep_ln_b,
                                 rec_edge, pep_bf);
  k_ga<<<512, 64, 0, stream>>>(rec_edge, pep_bf, WB, ga_bp, ga_bv,
                               pool_ln_g, pool_ln_b, dbuf, logitsT);
  k_pool2<<<256, 256, 0, stream>>>(logitsT, dbuf, attp);
  k_final<<<1, 256, 0, stream>>>(attp, mlp_W, mlp_b, out);
}

// Round 10
// 315.057 us; speedup vs baseline: 1.0905x; 1.0905x over previous
//
#include <hip/hip_runtime.h>
#include <hip/hip_bf16.h>

// FeatureExtractionModel on MI355X — round 10.
// k_emb v6: global_load_lds direct-to-LDS staging of ALL 10 K-groups (80KB),
//           source-swizzled (16B-unit XOR by row&7) for conflict-free b128 reads,
//           single vmcnt drain, cross-block TLP hides HBM latency.
// k_ga v4 : unchanged (LDS-staged layer-invariant rec_edge frags).

typedef __attribute__((ext_vector_type(8))) short bf16x8;
typedef __attribute__((ext_vector_type(4))) float f32x4;

#define MFMA(a, b, c) __builtin_amdgcn_mfma_f32_16x16x32_bf16((a), (b), (c), 0, 0, 0)

#define WB_REC_OFF   0
#define WB_PEP_OFF   83968
#define WB_EDGE_OFF  167936
#define WB_P_OFF     169984
#define WB_R_OFF     186368
#define WB_V_OFF     219136
#define WB_W0_OFF    251904
#define WB_W1_OFF    256000
#define WB_W2_OFF    258048
#define WB_TOTAL     258560

__device__ __forceinline__ unsigned short f2bf(float x) {
  __hip_bfloat16 h = __float2bfloat16(x);
  return __builtin_bit_cast(unsigned short, h);
}
__device__ __forceinline__ float bf2f(unsigned short u) {
  unsigned int t = ((unsigned int)u) << 16;
  return __builtin_bit_cast(float, t);
}
__device__ __forceinline__ bf16x8 loadBc(const unsigned short* base, int chunk, int lane) {
  return *(const bf16x8*)(base + ((size_t)chunk * 64 + lane) * 8);
}
__device__ __forceinline__ float tanhf_fast(float x) {
  float e = __expf(2.f * x);
  return 1.f - 2.f / (e + 1.f);
}

// ---------------- pack all B-operand fragments to bf16 (inline ESM combine) ----------------
__global__ __launch_bounds__(256) void k_pack(
    const float* __restrict__ Wresm, const float* __restrict__ Wpesm,
    const float* __restrict__ Wre, const float* __restrict__ Wpe,
    const float* __restrict__ Wedge, const float* __restrict__ Wp,
    const float* __restrict__ Wr, const float* __restrict__ Wv,
    const float* __restrict__ W0, const float* __restrict__ W1,
    const float* __restrict__ W2, unsigned short* __restrict__ WB) {
  const int t = blockIdx.x * 256 + threadIdx.x;
  if (t >= WB_TOTAL) return;
  float v = 0.f;
  if (t < WB_EDGE_OFF) {
    bool isPep = (t >= WB_PEP_OFF);
    int u = isPep ? (t - WB_PEP_OFF) : t;
    int j = u & 7, lane = (u >> 3) & 63, n = (u >> 9) & 3, kc = u >> 11;
    int k = kc * 32 + ((lane >> 4) << 3) + j;
    int col = n * 16 + (lane & 15);
    if (kc < 40) {
      const float* wemb = isPep ? (Wpe + col * 91 + 27) : (Wre + col * 85 + 21);
      const float* wesm = isPep ? Wpesm : Wresm;
      float s = 0.f;
#pragma unroll 8
      for (int e = 0; e < 64; ++e) s += wemb[e] * wesm[e * 1280 + k];
      v = s;
    } else {
      int kl = k - 1280;
      if (isPep) v = (kl < 27) ? Wpe[col * 91 + kl] : 0.f;
      else       v = (kl < 21) ? Wre[col * 85 + kl] : 0.f;
    }
  } else if (t < WB_P_OFF) {
    int u = t - WB_EDGE_OFF;
    int j = u & 7, lane = (u >> 3) & 63, n = (u >> 9) & 3;
    v = Wedge[(n * 16 + (lane & 15)) * 32 + ((lane >> 4) << 3) + j];
  } else if (t < WB_R_OFF) {
    int u = t - WB_P_OFF;
    int l = u >> 12, w = u & 4095;
    int j = w & 7, lane = (w >> 3) & 63, n = (w >> 9) & 3, kc = w >> 11;
    int o = kc * 32 + ((lane >> 4) << 3) + j;
    int d = n * 16 + (lane & 15);
    v = Wp[l * 4096 + d * 64 + o];
  } else if (t < WB_V_OFF) {
    int u = t - WB_R_OFF;
    int l = u >> 13, w = u & 8191;
    int j = w & 7, lane = (w >> 3) & 63, c = (w >> 9) & 15;
    int kc = c >> 3, n = c & 7;
    int o = kc * 32 + ((lane >> 4) << 3) + j;
    int k = n * 16 + (lane & 15);
    v = Wr[l * 8192 + o * 128 + k];
  } else if (t < WB_W0_OFF) {
    int u = t - WB_V_OFF;
    int l = u >> 13, w = u & 8191;
    int j = w & 7, lane = (w >> 3) & 63, n = (w >> 9) & 3, kc = w >> 11;
    int k = kc * 32 + ((lane >> 4) << 3) + j;
    int d = n * 16 + (lane & 15);
    v = Wv[l * 8192 + d * 128 + k];
  } else if (t < WB_W1_OFF) {
    int u = t - WB_W0_OFF;
    int j = u & 7, lane = (u >> 3) & 63, c = u >> 9;
    int kc = c >> 2, n = c & 3;
    v = W0[(n * 16 + (lane & 15)) * 64 + kc * 32 + ((lane >> 4) << 3) + j];
  } else if (t < WB_W2_OFF) {
    int u = t - WB_W1_OFF;
    int j = u & 7, lane = (u >> 3) & 63, c = u >> 9;
    int kc = c >> 1, n = c & 1;
    v = W1[(n * 16 + (lane & 15)) * 64 + kc * 32 + ((lane >> 4) << 3) + j];
  } else {
    int u = t - WB_W2_OFF;
    int j = u & 7, lane = (u >> 3) & 63;
    v = W2[(lane & 15) * 32 + ((lane >> 4) << 3) + j];
  }
  WB[t] = f2bf(v);
}

// ---------------- k_emb v6: 16 rows/block, full-depth global_load_lds staging ----------------
// rec tiles: bid in [0,5120); pep tiles: [5120,5632)
__global__ __launch_bounds__(64) void k_emb(
    const float* __restrict__ rec_feat, const float* __restrict__ edge_feat,
    const float* __restrict__ pep_feat, const unsigned short* __restrict__ WB,
    const float* __restrict__ rec_g, const float* __restrict__ rec_b,
    const float* __restrict__ pep_g, const float* __restrict__ pep_b,
    unsigned short* __restrict__ rec_edge, unsigned short* __restrict__ pep_out) {
  __shared__ float stg[20480];  // 80KB: [10 g][16 r][128 f32], 16B units src-swizzled by r&7
  const int bid = blockIdx.x;
  const int lane = threadIdx.x;
  const int quad = lane >> 4, lr = lane & 15;
  const bool isPep = (bid >= 5120);
  const int brow = (isPep ? bid - 5120 : bid) * 16;
  const float* __restrict__ src = isPep ? pep_feat : rec_feat;
  const int rowlen = isPep ? 1307 : 1322;
  const int head = isPep ? 27 : 42;
  const unsigned short* WBb = WB + (isPep ? WB_PEP_OFF : WB_REC_OFF);

  // ---- stage: 320 x global_load_lds (4B), LDS dest linear, source swizzled ----
  const int ul = lane >> 2;   // 16B-unit sub-index within half-row (0..15)
  const int fl = lane & 3;    // float within 16B unit
#pragma unroll
  for (int r = 0; r < 16; ++r) {
    const float* rowp = src + (size_t)(brow + r) * rowlen + head;
    const int s = r & 7;
#pragma unroll
    for (int h = 0; h < 2; ++h) {
      const int gu = (((h << 4) | ul) ^ s) * 4 + fl;  // swizzled float idx in 128-col group
#pragma unroll
      for (int g = 0; g < 10; ++g) {
        __builtin_amdgcn_global_load_lds(
            (const __attribute__((address_space(1))) void*)(rowp + g * 128 + gu),
            (__attribute__((address_space(3))) void*)(&stg[g * 2048 + r * 128 + h * 64]),
            4, 0, 0);
      }
    }
  }

  const f32x4 fz = {0.f, 0.f, 0.f, 0.f};
  f32x4 acc[4] = {fz, fz, fz, fz};

  // ---- compute: 10 groups x 4 chunks (compiler inserts the vmcnt drain once) ----
#pragma unroll
  for (int g = 0; g < 10; ++g) {
#pragma unroll
    for (int kc = 0; kc < 4; ++kc) {
      const int u0 = kc * 8 + quad * 2;           // logical 16B unit (even)
      const int sw = lr & 7;
      const float4 f0 = *(const float4*)&stg[g * 2048 + lr * 128 + ((u0 ^ sw) << 2)];
      const float4 f1 = *(const float4*)&stg[g * 2048 + lr * 128 + (((u0 | 1) ^ sw) << 2)];
      bf16x8 a;
#pragma unroll
      for (int j = 0; j < 4; ++j) { a[j] = (short)f2bf(f0[j]); a[4 + j] = (short)f2bf(f1[j]); }
#pragma unroll
      for (int n = 0; n < 4; ++n)
        acc[n] = MFMA(a, loadBc(WBb, g * 16 + kc * 4 + n, lane), acc[n]);
    }
  }
  {  // head chunk kc=40 (B zero-padded past real head cols)
    const float* p = src + (size_t)(brow + lr) * rowlen + quad * 8;
    bf16x8 a;
    if (!isPep) {
#pragma unroll
      for (int m = 0; m < 4; ++m) {
        const float2 v = *(const float2*)(p + 2 * m);
        a[2 * m] = (short)f2bf(v.x); a[2 * m + 1] = (short)f2bf(v.y);
      }
    } else {
#pragma unroll
      for (int j = 0; j < 8; ++j) a[j] = (short)f2bf(p[j]);
    }
#pragma unroll
    for (int n = 0; n < 4; ++n)
      acc[n] = MFMA(a, loadBc(WBb, 160 + n, lane), acc[n]);
  }

  // LN stats
  float s[4], sq[4];
#pragma unroll
  for (int i = 0; i < 4; ++i) {
    s[i] = acc[0][i] + acc[1][i] + acc[2][i] + acc[3][i];
    sq[i] = acc[0][i] * acc[0][i] + acc[1][i] * acc[1][i] +
            acc[2][i] * acc[2][i] + acc[3][i] * acc[3][i];
  }
#pragma unroll
  for (int msk = 1; msk < 16; msk <<= 1) {
#pragma unroll
    for (int i = 0; i < 4; ++i) {
      s[i] += __shfl_xor(s[i], msk);
      sq[i] += __shfl_xor(sq[i], msk);
    }
  }
  const float* gp = isPep ? pep_g : rec_g;
  const float* bp = isPep ? pep_b : rec_b;
  float gv[4], bvl[4];
#pragma unroll
  for (int n = 0; n < 4; ++n) { gv[n] = gp[lr + 16 * n]; bvl[n] = bp[lr + 16 * n]; }

  if (!isPep) {
    f32x4 acce[4] = {fz, fz, fz, fz};
    {
      const float* p = edge_feat + (size_t)(brow + lr) * 32 + quad * 8;
      const float4 f0 = *(const float4*)(p);
      const float4 f1 = *(const float4*)(p + 4);
      bf16x8 a;
#pragma unroll
      for (int j = 0; j < 4; ++j) { a[j] = (short)f2bf(f0[j]); a[4 + j] = (short)f2bf(f1[j]); }
#pragma unroll
      for (int n = 0; n < 4; ++n) acce[n] = MFMA(a, loadBc(WB + WB_EDGE_OFF, n, lane), acce[n]);
    }
#pragma unroll
    for (int i = 0; i < 4; ++i) {
      const float mean = s[i] * (1.f / 64.f);
      const float var = sq[i] * (1.f / 64.f) - mean * mean;
      const float rstd = rsqrtf(var + 1e-5f);
      unsigned short* dst = rec_edge + (size_t)(brow + quad * 4 + i) * 128;
#pragma unroll
      for (int n = 0; n < 4; ++n) {
        dst[lr + 16 * n] = f2bf((acc[n][i] - mean) * rstd * gv[n] + bvl[n]);
        dst[64 + lr + 16 * n] = f2bf(acce[n][i]);
      }
    }
  } else {
#pragma unroll
    for (int i = 0; i < 4; ++i) {
      const float mean = s[i] * (1.f / 64.f);
      const float var = sq[i] * (1.f / 64.f) - mean * mean;
      const float rstd = rsqrtf(var + 1e-5f);
      unsigned short* dst = pep_out + (size_t)(brow + quad * 4 + i) * 64;
#pragma unroll
      for (int n = 0; n < 4; ++n)
        dst[lr + 16 * n] = f2bf((acc[n][i] - mean) * rstd * gv[n] + bvl[n]);
    }
  }
}

// ---------------- k_ga v4: one-time LDS staging of rec_edge frags (p-inner layout) ----------------
__global__ __launch_bounds__(64) void k_ga(
    const unsigned short* __restrict__ rec_edge, const unsigned short* __restrict__ pep_bf,
    const unsigned short* __restrict__ WB,
    const float* __restrict__ ga_bp, const float* __restrict__ ga_bv,
    const float* __restrict__ pool_g, const float* __restrict__ pool_b,
    float* __restrict__ dbuf, float* __restrict__ logitsT) {
  __shared__ unsigned short rf_s[20480];  // 40KB: [10r][16c][16p] 16B units, p-inner
  __shared__ unsigned short pep_s[1024];
  __shared__ unsigned short q_s[1024];
  __shared__ unsigned short zs[2048];
  __shared__ float bias_s[512];

  const int lane = threadIdx.x;
  const int quad = lane >> 4, lr = lane & 15;
  const int swz = lr & 7;
  const int pbase = blockIdx.x * 16;
  const f32x4 fz = {0.f, 0.f, 0.f, 0.f};

#pragma unroll
  for (int i = 0; i < 4; ++i) {
    int f = lane + 64 * i;
    bias_s[f] = ga_bp[f];
    bias_s[256 + f] = ga_bv[f];
  }
#pragma unroll
  for (int i = 0; i < 2; ++i) {
    const int G = lane + 64 * i;
    const int p = G >> 3, gg = G & 7;
    const bf16x8 v = *(const bf16x8*)(pep_bf + (size_t)(pbase + p) * 64 + gg * 8);
    *(bf16x8*)(pep_s + p * 64 + ((gg ^ (p & 7)) << 3)) = v;
  }
  const unsigned short* reb = rec_edge + (size_t)(pbase + lr) * 1280 + quad * 8;
#pragma unroll
  for (int r = 0; r < 10; ++r)
#pragma unroll
    for (int kc = 0; kc < 4; ++kc)
      *(bf16x8*)(rf_s + ((r * 16 + quad + 4 * kc) * 16 + lr) * 8) =
          *(const bf16x8*)(reb + r * 128 + kc * 32);
  auto rfrag = [&](int r, int kc) -> bf16x8 {
    return *(const bf16x8*)(rf_s + ((r * 16 + quad + 4 * kc) * 16 + lr) * 8);
  };

  auto bwrite = [&](unsigned short* buf, int p, int col, unsigned short val) {
    buf[p * 64 + ((((col >> 3)) ^ (p & 7)) << 3) + (col & 7)] = val;
  };
  auto bfrag = [&](const unsigned short* buf, int kc) -> bf16x8 {
    return *(const bf16x8*)(buf + lr * 64 + ((((kc << 2) + quad) ^ swz) << 3));
  };

  f32x4 pcur[4];
  for (int l = 0; l < 4; ++l) {
    const unsigned short* WBp = WB + WB_P_OFF + l * 4096;
    const unsigned short* WBr = WB + WB_R_OFF + l * 8192;
    const unsigned short* WBv = WB + WB_V_OFF + l * 8192;
    f32x4 qa[4] = {fz, fz, fz, fz};
#pragma unroll
    for (int kc = 0; kc < 2; ++kc) {
      bf16x8 a = bfrag(pep_s, kc);
#pragma unroll
      for (int n = 0; n < 4; ++n) qa[n] = MFMA(a, loadBc(WBp, kc * 4 + n, lane), qa[n]);
    }
#pragma unroll
    for (int n = 0; n < 4; ++n) {
      const float bpv = bias_s[l * 64 + lr + 16 * n];
#pragma unroll
      for (int i = 0; i < 4; ++i) qa[n][i] += bpv;
    }
#pragma unroll
    for (int n = 0; n < 4; ++n)
#pragma unroll
      for (int i = 0; i < 4; ++i)
        bwrite(q_s, quad * 4 + i, lr + 16 * n, f2bf(qa[n][i]));
    const bf16x8 aq0 = bfrag(q_s, 0), aq1 = bfrag(q_s, 1);
    f32x4 za[8] = {fz, fz, fz, fz, fz, fz, fz, fz};
#pragma unroll
    for (int n = 0; n < 8; ++n) za[n] = MFMA(aq0, loadBc(WBr, n, lane), za[n]);
#pragma unroll
    for (int n = 0; n < 8; ++n) za[n] = MFMA(aq1, loadBc(WBr, 8 + n, lane), za[n]);
#pragma unroll
    for (int n = 0; n < 8; ++n)
#pragma unroll
      for (int i = 0; i < 4; ++i) {
        const int p = quad * 4 + i, k = 16 * n + lr;
        zs[p * 128 + ((((k >> 3) ^ (p & 7)) << 3) | (k & 7))] = f2bf(za[n][i]);
      }
    float zf[4][8];
#pragma unroll
    for (int kc = 0; kc < 4; ++kc) {
      const bf16x8 z8 = *(const bf16x8*)(zs + lr * 128 + (((quad + 4 * kc) ^ swz) << 3));
#pragma unroll
      for (int j = 0; j < 8; ++j) zf[kc][j] = bf2f((unsigned short)z8[j]);
    }
    float lg[10];
#pragma unroll
    for (int r = 0; r < 10; ++r) {
      float part = 0.f;
#pragma unroll
      for (int kc = 0; kc < 4; ++kc) {
        const bf16x8 rf = rfrag(r, kc);
#pragma unroll
        for (int j = 0; j < 8; ++j) part += bf2f((unsigned short)rf[j]) * zf[kc][j];
      }
      part += __shfl_xor(part, 16);
      part += __shfl_xor(part, 32);
      lg[r] = part * 0.125f;
    }
    float mx = lg[0];
#pragma unroll
    for (int r = 1; r < 10; ++r) mx = fmaxf(mx, lg[r]);
    float ssum = 0.f;
#pragma unroll
    for (int r = 0; r < 10; ++r) { lg[r] = __expf(lg[r] - mx); ssum += lg[r]; }
    const float inv = 1.f / ssum;
#pragma unroll
    for (int r = 0; r < 10; ++r) lg[r] *= inv;
    float wsacc[4][8] = {};
#pragma unroll
    for (int r = 0; r < 10; ++r) {
#pragma unroll
      for (int kc = 0; kc < 4; ++kc) {
        const bf16x8 rf = rfrag(r, kc);
#pragma unroll
        for (int j = 0; j < 8; ++j)
          wsacc[kc][j] += lg[r] * bf2f((unsigned short)rf[j]);
      }
    }
    bf16x8 wf[4];
#pragma unroll
    for (int kc = 0; kc < 4; ++kc)
#pragma unroll
      for (int j = 0; j < 8; ++j) wf[kc][j] = (short)f2bf(wsacc[kc][j]);
    f32x4 oa[4] = {fz, fz, fz, fz};
#pragma unroll
    for (int kc = 0; kc < 4; ++kc)
#pragma unroll
      for (int n = 0; n < 4; ++n) oa[n] = MFMA(wf[kc], loadBc(WBv, kc * 4 + n, lane), oa[n]);
#pragma unroll
    for (int n = 0; n < 4; ++n) {
      const float bvv = bias_s[256 + l * 64 + lr + 16 * n];
#pragma unroll
      for (int i = 0; i < 4; ++i) pcur[n][i] = qa[n][i] + oa[n][i] + bvv;
    }
#pragma unroll
    for (int n = 0; n < 4; ++n)
#pragma unroll
      for (int i = 0; i < 4; ++i)
        bwrite(pep_s, quad * 4 + i, lr + 16 * n, f2bf(pcur[n][i]));
  }

  {
    float s[4], sq[4];
#pragma unroll
    for (int i = 0; i < 4; ++i) {
      s[i] = pcur[0][i] + pcur[1][i] + pcur[2][i] + pcur[3][i];
      sq[i] = pcur[0][i] * pcur[0][i] + pcur[1][i] * pcur[1][i] +
              pcur[2][i] * pcur[2][i] + pcur[3][i] * pcur[3][i];
    }
#pragma unroll
    for (int msk = 1; msk < 16; msk <<= 1) {
#pragma unroll
      for (int i = 0; i < 4; ++i) {
        s[i] += __shfl_xor(s[i], msk);
        sq[i] += __shfl_xor(sq[i], msk);
      }
    }
    float gv[4], bv2[4];
#pragma unroll
    for (int n = 0; n < 4; ++n) { gv[n] = pool_g[lr + 16 * n]; bv2[n] = pool_b[lr + 16 * n]; }
    f32x4 d[4];
#pragma unroll
    for (int i = 0; i < 4; ++i) {
      const float mean = s[i] * (1.f / 64.f);
      const float var = sq[i] * (1.f / 64.f) - mean * mean;
      const float rstd = rsqrtf(var + 1e-5f);
#pragma unroll
      for (int n = 0; n < 4; ++n) d[n][i] = (pcur[n][i] - mean) * rstd * gv[n] + bv2[n];
    }
    float* zf32 = (float*)zs;
#pragma unroll
    for (int n = 0; n < 4; ++n)
#pragma unroll
      for (int i = 0; i < 4; ++i)
        zf32[(quad * 4 + i) * 64 + lr + 16 * n] = d[n][i];
#pragma unroll
    for (int i = 0; i < 4; ++i) {
      const float4 v = *(const float4*)(&zf32[i * 256 + lane * 4]);
      *(float4*)(dbuf + (size_t)pbase * 64 + i * 256 + lane * 4) = v;
    }
#pragma unroll
    for (int n = 0; n < 4; ++n)
#pragma unroll
      for (int i = 0; i < 4; ++i)
        bwrite(q_s, quad * 4 + i, lr + 16 * n, f2bf(d[n][i]));
    const bf16x8 ad0 = bfrag(q_s, 0), ad1 = bfrag(q_s, 1);
    f32x4 h0[4] = {fz, fz, fz, fz};
#pragma unroll
    for (int n = 0; n < 4; ++n) {
      h0[n] = MFMA(ad0, loadBc(WB + WB_W0_OFF, n, lane), h0[n]);
      h0[n] = MFMA(ad1, loadBc(WB + WB_W0_OFF, 4 + n, lane), h0[n]);
    }
#pragma unroll
    for (int n = 0; n < 4; ++n)
#pragma unroll
      for (int i = 0; i < 4; ++i)
        bwrite(q_s, quad * 4 + i, lr + 16 * n, f2bf(tanhf_fast(h0[n][i])));
    const bf16x8 ah00 = bfrag(q_s, 0), ah01 = bfrag(q_s, 1);
    f32x4 h1[2] = {fz, fz};
#pragma unroll
    for (int n = 0; n < 2; ++n) {
      h1[n] = MFMA(ah00, loadBc(WB + WB_W1_OFF, n, lane), h1[n]);
      h1[n] = MFMA(ah01, loadBc(WB + WB_W1_OFF, 2 + n, lane), h1[n]);
    }
#pragma unroll
    for (int n = 0; n < 2; ++n)
#pragma unroll
      for (int i = 0; i < 4; ++i)
        bwrite(q_s, quad * 4 + i, lr + 16 * n, f2bf(tanhf_fast(h1[n][i])));
    const bf16x8 ah1 = bfrag(q_s, 0);
    f32x4 lac = MFMA(ah1, loadBc(WB + WB_W2_OFF, 0, lane), fz);
    const int b = pbase >> 11, sx0 = pbase & 2047;
#pragma unroll
    for (int i = 0; i < 4; ++i)
      logitsT[(size_t)(b * 16 + lr) * 2048 + sx0 + quad * 4 + i] = lac[i];
  }
}

// ---------------- pool2: 256 blocks, redundant softmax stats + partials ----------------
__global__ __launch_bounds__(256) void k_pool2(
    const float* __restrict__ logitsT, const float* __restrict__ dbuf,
    float* __restrict__ attp) {
  __shared__ float sh[2048];
  __shared__ float red[8];
  __shared__ float part[16][64];
  const int blk = blockIdx.x;
  const int bh = blk >> 2, q = blk & 3;
  const int b = bh >> 4;
  const int tid = threadIdx.x, lane = tid & 63, wid = tid >> 6;
  const float* lrow = logitsT + (size_t)bh * 2048;

  float m = -1e30f;
  for (int sx = tid; sx < 2048; sx += 256) {
    float v = lrow[sx];
    sh[sx] = v;
    m = fmaxf(m, v);
  }
#pragma unroll
  for (int msk = 1; msk < 64; msk <<= 1) m = fmaxf(m, __shfl_xor(m, msk));
  if (lane == 0) red[wid] = m;
  __syncthreads();
  m = fmaxf(fmaxf(red[0], red[1]), fmaxf(red[2], red[3]));

  float s1 = 0.f;
  for (int sx = tid; sx < 2048; sx += 256) {
    float e = __expf(sh[sx] - m);
    sh[sx] = e;
    s1 += e;
  }
#pragma unroll
  for (int msk = 1; msk < 64; msk <<= 1) s1 += __shfl_xor(s1, msk);
  __syncthreads();
  if (lane == 0) red[4 + wid] = s1;
  __syncthreads();
  s1 = red[4] + red[5] + red[6] + red[7];
  const float invS1 = 1.f / s1;

  float s2 = 0.f;
  for (int sx = tid; sx < 2048; sx += 256) {
    float e2 = __expf((sh[sx] - 1.f) * invS1);
    sh[sx] = e2;
    s2 += e2;
  }
#pragma unroll
  for (int msk = 1; msk < 64; msk <<= 1) s2 += __shfl_xor(s2, msk);
  __syncthreads();
  if (lane == 0) red[wid] = s2;
  __syncthreads();
  s2 = red[0] + red[1] + red[2] + red[3];
  const float invS2 = 1.f / s2;

  const int d16 = tid & 15, sxg = tid >> 4;
  float4 a4 = {0.f, 0.f, 0.f, 0.f};
  const float* db = dbuf + (size_t)b * 2048 * 64 + d16 * 4;
#pragma unroll 4
  for (int sx = q * 512 + sxg; sx < (q + 1) * 512; sx += 16) {
    const float w = sh[sx];
    const float4 v = *(const float4*)(db + (size_t)sx * 64);
    a4.x += w * v.x; a4.y += w * v.y; a4.z += w * v.z; a4.w += w * v.w;
  }
  *(float4*)(&part[sxg][d16 * 4]) = a4;
  __syncthreads();
  if (tid < 64) {
    float s = 0.f;
#pragma unroll
    for (int g2 = 0; g2 < 16; ++g2) s += part[g2][tid];
    attp[(size_t)(bh * 4 + q) * 64 + tid] = s * invS2;
  }
}

// ---------------- final: reduce partials, mean over heads, project ----------------
__global__ __launch_bounds__(256) void k_final(
    const float* __restrict__ attp, const float* __restrict__ W,
    const float* __restrict__ bias, float* __restrict__ out) {
  __shared__ float pooled[4][64];
  const int tid = threadIdx.x;
  {
    const int b = tid >> 6, d = tid & 63;
    float s = 0.f;
#pragma unroll
    for (int hq = 0; hq < 64; ++hq) s += attp[((size_t)b * 64 + hq) * 64 + d];
    pooled[b][d] = s * (1.f / 16.f);
  }
  __syncthreads();
  if (tid < 128) {
    const int b = tid >> 5, j = tid & 31;
    float s = bias[j];
#pragma unroll
    for (int d2 = 0; d2 < 64; ++d2) s += pooled[b][d2] * W[j * 64 + d2];
    out[b * 32 + j] = s;
  }
}

extern "C" void kernel_launch(void* const* d_in, const int* in_sizes, int n_in,
                              void* d_out, int out_size, void* d_ws, size_t ws_size,
                              hipStream_t stream) {
  const float* pep_feat = (const float*)d_in[0];
  const float* rec_feat = (const float*)d_in[1];
  const float* edge_feat = (const float*)d_in[2];
  const float* W_rec_esm = (const float*)d_in[3];
  const float* W_pep_esm = (const float*)d_in[4];
  const float* W_pep_emb = (const float*)d_in[5];
  const float* W_rec_emb = (const float*)d_in[6];
  const float* W_edge_emb = (const float*)d_in[7];
  const float* pep_ln_g = (const float*)d_in[8];
  const float* pep_ln_b = (const float*)d_in[9];
  const float* rec_ln_g = (const float*)d_in[10];
  const float* rec_ln_b = (const float*)d_in[11];
  const float* ga_Wp = (const float*)d_in[12];
  const float* ga_bp = (const float*)d_in[13];
  const float* ga_Wr = (const float*)d_in[14];
  const float* ga_br = (const float*)d_in[15];
  const float* ga_Wv = (const float*)d_in[16];
  const float* ga_bv = (const float*)d_in[17];
  const float* pool_ln_g = (const float*)d_in[18];
  const float* pool_ln_b = (const float*)d_in[19];
  const float* pool_W0 = (const float*)d_in[20];
  const float* pool_W1 = (const float*)d_in[21];
  const float* pool_W2 = (const float*)d_in[22];
  const float* mlp_W = (const float*)d_in[23];
  const float* mlp_b = (const float*)d_in[24];
  float* out = (float*)d_out;
  (void)ga_br;  // softmax-invariant, algebraically dropped
  (void)ws_size; (void)in_sizes; (void)n_in; (void)out_size;

  char* ws = (char*)d_ws;
  unsigned short* WB = (unsigned short*)(ws);
  unsigned short* rec_edge = (unsigned short*)(ws + 524288);
  unsigned short* pep_bf = (unsigned short*)(ws + 21495808);
  float* dbuf = (float*)(ws + 22544384);
  float* logitsT = (float*)(ws + 24641536);
  float* attp = (float*)(ws + 25165824);

  k_pack<<<1010, 256, 0, stream>>>(W_rec_esm, W_pep_esm, W_rec_emb, W_pep_emb,
                                   W_edge_emb, ga_Wp, ga_Wr, ga_Wv,
                                   pool_W0, pool_W1, pool_W2, WB);
  k_emb<<<5632, 64, 0, stream>>>(rec_feat, edge_feat, pep_feat, WB,
                                 rec_ln_g, rec_ln_b, pep_ln_g, pep_ln_b,
                                 rec_edge, pep_bf);
  k_ga<<<512, 64, 0, stream>>>(rec_edge, pep_bf, WB, ga_bp, ga_bv,
                               pool_ln_g, pool_ln_b, dbuf, logitsT);
  k_pool2<<<256, 256, 0, stream>>>(logitsT, dbuf, attp);
  k_final<<<1, 256, 0, stream>>>(attp, mlp_W, mlp_b, out);
}

// Round 11
// 190.895 us; speedup vs baseline: 1.7997x; 1.6504x over previous
//
#include <hip/hip_runtime.h>
#include <hip/hip_bf16.h>

// FeatureExtractionModel on MI355X — round 11: best-of reassembly.
// k_emb  = v3 (R8): 16 rows/single-wave block, float2 register staging,
//          2-buf 16KB f32 LDS, zero barriers. Measured-budget ~84us (5.5TB/s).
// k_ga   = v2 (R7): direct global rec_edge frag reads per layer (L2-resident,
//          compiler-prefetchable), 10.2KB LDS. Measured 797/32 = ~25us.
// k_pool2= R10 partials version. k_pack/k_final unchanged.

typedef __attribute__((ext_vector_type(8))) short bf16x8;
typedef __attribute__((ext_vector_type(4))) float f32x4;

#define MFMA(a, b, c) __builtin_amdgcn_mfma_f32_16x16x32_bf16((a), (b), (c), 0, 0, 0)

#define WB_REC_OFF   0
#define WB_PEP_OFF   83968
#define WB_EDGE_OFF  167936
#define WB_P_OFF     169984
#define WB_R_OFF     186368
#define WB_V_OFF     219136
#define WB_W0_OFF    251904
#define WB_W1_OFF    256000
#define WB_W2_OFF    258048
#define WB_TOTAL     258560

__device__ __forceinline__ unsigned short f2bf(float x) {
  __hip_bfloat16 h = __float2bfloat16(x);
  return __builtin_bit_cast(unsigned short, h);
}
__device__ __forceinline__ float bf2f(unsigned short u) {
  unsigned int t = ((unsigned int)u) << 16;
  return __builtin_bit_cast(float, t);
}
__device__ __forceinline__ bf16x8 loadBc(const unsigned short* base, int chunk, int lane) {
  return *(const bf16x8*)(base + ((size_t)chunk * 64 + lane) * 8);
}
__device__ __forceinline__ float tanhf_fast(float x) {
  float e = __expf(2.f * x);
  return 1.f - 2.f / (e + 1.f);
}
__device__ __forceinline__ int swzr(int r) {  // 16B-unit XOR swizzle bits for row r
  return (r & 1) | (((r >> 1) & 7) << 2);
}

// ---------------- pack all B-operand fragments to bf16 (inline ESM combine) ----------------
__global__ __launch_bounds__(256) void k_pack(
    const float* __restrict__ Wresm, const float* __restrict__ Wpesm,
    const float* __restrict__ Wre, const float* __restrict__ Wpe,
    const float* __restrict__ Wedge, const float* __restrict__ Wp,
    const float* __restrict__ Wr, const float* __restrict__ Wv,
    const float* __restrict__ W0, const float* __restrict__ W1,
    const float* __restrict__ W2, unsigned short* __restrict__ WB) {
  const int t = blockIdx.x * 256 + threadIdx.x;
  if (t >= WB_TOTAL) return;
  float v = 0.f;
  if (t < WB_EDGE_OFF) {
    bool isPep = (t >= WB_PEP_OFF);
    int u = isPep ? (t - WB_PEP_OFF) : t;
    int j = u & 7, lane = (u >> 3) & 63, n = (u >> 9) & 3, kc = u >> 11;
    int k = kc * 32 + ((lane >> 4) << 3) + j;
    int col = n * 16 + (lane & 15);
    if (kc < 40) {
      const float* wemb = isPep ? (Wpe + col * 91 + 27) : (Wre + col * 85 + 21);
      const float* wesm = isPep ? Wpesm : Wresm;
      float s = 0.f;
#pragma unroll 8
      for (int e = 0; e < 64; ++e) s += wemb[e] * wesm[e * 1280 + k];
      v = s;
    } else {
      int kl = k - 1280;
      if (isPep) v = (kl < 27) ? Wpe[col * 91 + kl] : 0.f;
      else       v = (kl < 21) ? Wre[col * 85 + kl] : 0.f;
    }
  } else if (t < WB_P_OFF) {
    int u = t - WB_EDGE_OFF;
    int j = u & 7, lane = (u >> 3) & 63, n = (u >> 9) & 3;
    v = Wedge[(n * 16 + (lane & 15)) * 32 + ((lane >> 4) << 3) + j];
  } else if (t < WB_R_OFF) {
    int u = t - WB_P_OFF;
    int l = u >> 12, w = u & 4095;
    int j = w & 7, lane = (w >> 3) & 63, n = (w >> 9) & 3, kc = w >> 11;
    int o = kc * 32 + ((lane >> 4) << 3) + j;
    int d = n * 16 + (lane & 15);
    v = Wp[l * 4096 + d * 64 + o];
  } else if (t < WB_V_OFF) {
    int u = t - WB_R_OFF;
    int l = u >> 13, w = u & 8191;
    int j = w & 7, lane = (w >> 3) & 63, c = (w >> 9) & 15;
    int kc = c >> 3, n = c & 7;
    int o = kc * 32 + ((lane >> 4) << 3) + j;
    int k = n * 16 + (lane & 15);
    v = Wr[l * 8192 + o * 128 + k];
  } else if (t < WB_W0_OFF) {
    int u = t - WB_V_OFF;
    int l = u >> 13, w = u & 8191;
    int j = w & 7, lane = (w >> 3) & 63, n = (w >> 9) & 3, kc = w >> 11;
    int k = kc * 32 + ((lane >> 4) << 3) + j;
    int d = n * 16 + (lane & 15);
    v = Wv[l * 8192 + d * 128 + k];
  } else if (t < WB_W1_OFF) {
    int u = t - WB_W0_OFF;
    int j = u & 7, lane = (u >> 3) & 63, c = u >> 9;
    int kc = c >> 2, n = c & 3;
    v = W0[(n * 16 + (lane & 15)) * 64 + kc * 32 + ((lane >> 4) << 3) + j];
  } else if (t < WB_W2_OFF) {
    int u = t - WB_W1_OFF;
    int j = u & 7, lane = (u >> 3) & 63, c = u >> 9;
    int kc = c >> 1, n = c & 1;
    v = W1[(n * 16 + (lane & 15)) * 64 + kc * 32 + ((lane >> 4) << 3) + j];
  } else {
    int u = t - WB_W2_OFF;
    int j = u & 7, lane = (u >> 3) & 63;
    v = W2[(lane & 15) * 32 + ((lane >> 4) << 3) + j];
  }
  WB[t] = f2bf(v);
}

// ---------------- k_emb v3 (R8): 16 rows per single-wave block ----------------
// rec tiles: bid in [0,5120); pep tiles: [5120,5632)
__global__ __launch_bounds__(64) void k_emb(
    const float* __restrict__ rec_feat, const float* __restrict__ edge_feat,
    const float* __restrict__ pep_feat, const unsigned short* __restrict__ WB,
    const float* __restrict__ rec_g, const float* __restrict__ rec_b,
    const float* __restrict__ pep_g, const float* __restrict__ pep_b,
    unsigned short* __restrict__ rec_edge, unsigned short* __restrict__ pep_out) {
  __shared__ float stg[2][16][128];  // 16 KB: 2 bufs x 16 rows x 512B
  const int bid = blockIdx.x;
  const int lane = threadIdx.x;
  const int quad = lane >> 4, lr = lane & 15;
  const bool isPep = (bid >= 5120);
  const int brow = (isPep ? bid - 5120 : bid) * 16;

  const f32x4 fz = {0.f, 0.f, 0.f, 0.f};
  f32x4 acc[4] = {fz, fz, fz, fz};

  auto frag = [&](int buf, int c) -> bf16x8 {
    const int u0 = c * 8 + quad * 2;
    const int s0 = u0 ^ swzr(lr), s1 = (u0 + 1) ^ swzr(lr);
    const float4 f0 = *(const float4*)((const char*)&stg[buf][lr][0] + s0 * 16);
    const float4 f1 = *(const float4*)((const char*)&stg[buf][lr][0] + s1 * 16);
    bf16x8 a;
#pragma unroll
    for (int j = 0; j < 4; ++j) { a[j] = (short)f2bf(f0[j]); a[4 + j] = (short)f2bf(f1[j]); }
    return a;
  };

  if (!isPep) {
    const float* base = rec_feat + (size_t)brow * 1322 + 42;
    float2 ld2[16];
    auto loadg = [&](int g) {
#pragma unroll
      for (int i = 0; i < 16; ++i)
        ld2[i] = *(const float2*)(base + (size_t)i * 1322 + g * 128 + lane * 2);
    };
    auto writeg = [&](int b) {
#pragma unroll
      for (int i = 0; i < 16; ++i) {
        const int su = (lane >> 1) ^ swzr(i);
        *(float2*)((char*)&stg[b][i][0] + su * 16 + (lane & 1) * 8) = ld2[i];
      }
    };
    loadg(0); writeg(0);
    int buf = 0;
    for (int g = 0; g < 10; ++g) {
      bf16x8 bb[16];
#pragma unroll
      for (int m = 0; m < 16; ++m) bb[m] = loadBc(WB + WB_REC_OFF, g * 16 + m, lane);
      if (g < 9) loadg(g + 1);
#pragma unroll
      for (int c = 0; c < 4; ++c) {
        const bf16x8 a = frag(buf, c);
#pragma unroll
        for (int n = 0; n < 4; ++n) acc[n] = MFMA(a, bb[c * 4 + n], acc[n]);
      }
      if (g < 9) writeg(buf ^ 1);
      buf ^= 1;
    }
    {  // head chunk kc=40
      const float* p = rec_feat + (size_t)(brow + lr) * 1322 + quad * 8;
      bf16x8 a;
#pragma unroll
      for (int m = 0; m < 4; ++m) {
        const float2 v = *(const float2*)(p + 2 * m);
        a[2 * m] = (short)f2bf(v.x); a[2 * m + 1] = (short)f2bf(v.y);
      }
#pragma unroll
      for (int n = 0; n < 4; ++n)
        acc[n] = MFMA(a, loadBc(WB + WB_REC_OFF, 160 + n, lane), acc[n]);
    }
  } else {
    const float* base = pep_feat + (size_t)brow * 1307 + 27;
    float ldp[32];
    auto loadg = [&](int g) {
#pragma unroll
      for (int i = 0; i < 16; ++i)
#pragma unroll
        for (int ph = 0; ph < 2; ++ph)
          ldp[i * 2 + ph] = base[(size_t)i * 1307 + g * 128 + ph * 64 + lane];
    };
    auto writeg = [&](int b) {
#pragma unroll
      for (int i = 0; i < 16; ++i)
#pragma unroll
        for (int ph = 0; ph < 2; ++ph) {
          const int su = (ph * 16 + (lane >> 2)) ^ swzr(i);
          *((float*)((char*)&stg[b][i][0] + su * 16 + (lane & 3) * 4)) = ldp[i * 2 + ph];
        }
    };
    loadg(0); writeg(0);
    int buf = 0;
    for (int g = 0; g < 10; ++g) {
      bf16x8 bb[16];
#pragma unroll
      for (int m = 0; m < 16; ++m) bb[m] = loadBc(WB + WB_PEP_OFF, g * 16 + m, lane);
      if (g < 9) loadg(g + 1);
#pragma unroll
      for (int c = 0; c < 4; ++c) {
        const bf16x8 a = frag(buf, c);
#pragma unroll
        for (int n = 0; n < 4; ++n) acc[n] = MFMA(a, bb[c * 4 + n], acc[n]);
      }
      if (g < 9) writeg(buf ^ 1);
      buf ^= 1;
    }
    {  // head chunk
      const float* p = pep_feat + (size_t)(brow + lr) * 1307 + quad * 8;
      bf16x8 a;
#pragma unroll
      for (int j = 0; j < 8; ++j) a[j] = (short)f2bf(p[j]);
#pragma unroll
      for (int n = 0; n < 4; ++n)
        acc[n] = MFMA(a, loadBc(WB + WB_PEP_OFF, 160 + n, lane), acc[n]);
    }
  }

  float s[4], sq[4];
#pragma unroll
  for (int i = 0; i < 4; ++i) {
    s[i] = acc[0][i] + acc[1][i] + acc[2][i] + acc[3][i];
    sq[i] = acc[0][i] * acc[0][i] + acc[1][i] * acc[1][i] +
            acc[2][i] * acc[2][i] + acc[3][i] * acc[3][i];
  }
#pragma unroll
  for (int msk = 1; msk < 16; msk <<= 1) {
#pragma unroll
    for (int i = 0; i < 4; ++i) {
      s[i] += __shfl_xor(s[i], msk);
      sq[i] += __shfl_xor(sq[i], msk);
    }
  }
  const float* gp = isPep ? pep_g : rec_g;
  const float* bp = isPep ? pep_b : rec_b;
  float gv[4], bvl[4];
#pragma unroll
  for (int n = 0; n < 4; ++n) { gv[n] = gp[lr + 16 * n]; bvl[n] = bp[lr + 16 * n]; }

  if (!isPep) {
    f32x4 acce[4] = {fz, fz, fz, fz};
    {
      const float* p = edge_feat + (size_t)(brow + lr) * 32 + quad * 8;
      const float4 f0 = *(const float4*)(p);
      const float4 f1 = *(const float4*)(p + 4);
      bf16x8 a;
#pragma unroll
      for (int j = 0; j < 4; ++j) { a[j] = (short)f2bf(f0[j]); a[4 + j] = (short)f2bf(f1[j]); }
#pragma unroll
      for (int n = 0; n < 4; ++n) acce[n] = MFMA(a, loadBc(WB + WB_EDGE_OFF, n, lane), acce[n]);
    }
#pragma unroll
    for (int i = 0; i < 4; ++i) {
      const float mean = s[i] * (1.f / 64.f);
      const float var = sq[i] * (1.f / 64.f) - mean * mean;
      const float rstd = rsqrtf(var + 1e-5f);
      unsigned short* dst = rec_edge + (size_t)(brow + quad * 4 + i) * 128;
#pragma unroll
      for (int n = 0; n < 4; ++n) {
        dst[lr + 16 * n] = f2bf((acc[n][i] - mean) * rstd * gv[n] + bvl[n]);
        dst[64 + lr + 16 * n] = f2bf(acce[n][i]);
      }
    }
  } else {
#pragma unroll
    for (int i = 0; i < 4; ++i) {
      const float mean = s[i] * (1.f / 64.f);
      const float var = sq[i] * (1.f / 64.f) - mean * mean;
      const float rstd = rsqrtf(var + 1e-5f);
      unsigned short* dst = pep_out + (size_t)(brow + quad * 4 + i) * 64;
#pragma unroll
      for (int n = 0; n < 4; ++n)
        dst[lr + 16 * n] = f2bf((acc[n][i] - mean) * rstd * gv[n] + bvl[n]);
    }
  }
}

// ---------------- k_ga v2 (R7): direct global rec_edge frag reads ----------------
__global__ __launch_bounds__(64) void k_ga(
    const unsigned short* __restrict__ rec_edge, const unsigned short* __restrict__ pep_bf,
    const unsigned short* __restrict__ WB,
    const float* __restrict__ ga_bp, const float* __restrict__ ga_bv,
    const float* __restrict__ pool_g, const float* __restrict__ pool_b,
    float* __restrict__ dbuf, float* __restrict__ logitsT) {
  __shared__ unsigned short pep_s[1024];
  __shared__ unsigned short q_s[1024];
  __shared__ unsigned short zs[2048];
  __shared__ float bias_s[512];

  const int lane = threadIdx.x;
  const int quad = lane >> 4, lr = lane & 15;
  const int swz = lr & 7;
  const int pbase = blockIdx.x * 16;
  const f32x4 fz = {0.f, 0.f, 0.f, 0.f};

#pragma unroll
  for (int i = 0; i < 4; ++i) {
    int f = lane + 64 * i;
    bias_s[f] = ga_bp[f];
    bias_s[256 + f] = ga_bv[f];
  }
#pragma unroll
  for (int i = 0; i < 2; ++i) {
    const int G = lane + 64 * i;
    const int p = G >> 3, gg = G & 7;
    const bf16x8 v = *(const bf16x8*)(pep_bf + (size_t)(pbase + p) * 64 + gg * 8);
    *(bf16x8*)(pep_s + p * 64 + ((gg ^ (p & 7)) << 3)) = v;
  }

  auto bwrite = [&](unsigned short* buf, int p, int col, unsigned short val) {
    buf[p * 64 + ((((col >> 3)) ^ (p & 7)) << 3) + (col & 7)] = val;
  };
  auto bfrag = [&](const unsigned short* buf, int kc) -> bf16x8 {
    return *(const bf16x8*)(buf + lr * 64 + ((((kc << 2) + quad) ^ swz) << 3));
  };
  const unsigned short* reb = rec_edge + (size_t)(pbase + lr) * 1280 + quad * 8;

  f32x4 pcur[4];
  for (int l = 0; l < 4; ++l) {
    const unsigned short* WBp = WB + WB_P_OFF + l * 4096;
    const unsigned short* WBr = WB + WB_R_OFF + l * 8192;
    const unsigned short* WBv = WB + WB_V_OFF + l * 8192;
    f32x4 qa[4] = {fz, fz, fz, fz};
#pragma unroll
    for (int kc = 0; kc < 2; ++kc) {
      bf16x8 a = bfrag(pep_s, kc);
#pragma unroll
      for (int n = 0; n < 4; ++n) qa[n] = MFMA(a, loadBc(WBp, kc * 4 + n, lane), qa[n]);
    }
#pragma unroll
    for (int n = 0; n < 4; ++n) {
      const float bpv = bias_s[l * 64 + lr + 16 * n];
#pragma unroll
      for (int i = 0; i < 4; ++i) qa[n][i] += bpv;
    }
#pragma unroll
    for (int n = 0; n < 4; ++n)
#pragma unroll
      for (int i = 0; i < 4; ++i)
        bwrite(q_s, quad * 4 + i, lr + 16 * n, f2bf(qa[n][i]));
    const bf16x8 aq0 = bfrag(q_s, 0), aq1 = bfrag(q_s, 1);
    f32x4 za[8] = {fz, fz, fz, fz, fz, fz, fz, fz};
#pragma unroll
    for (int n = 0; n < 8; ++n) za[n] = MFMA(aq0, loadBc(WBr, n, lane), za[n]);
#pragma unroll
    for (int n = 0; n < 8; ++n) za[n] = MFMA(aq1, loadBc(WBr, 8 + n, lane), za[n]);
#pragma unroll
    for (int n = 0; n < 8; ++n)
#pragma unroll
      for (int i = 0; i < 4; ++i) {
        const int p = quad * 4 + i, k = 16 * n + lr;
        zs[p * 128 + ((((k >> 3) ^ (p & 7)) << 3) | (k & 7))] = f2bf(za[n][i]);
      }
    float zf[4][8];
#pragma unroll
    for (int kc = 0; kc < 4; ++kc) {
      const bf16x8 z8 = *(const bf16x8*)(zs + lr * 128 + (((quad + 4 * kc) ^ swz) << 3));
#pragma unroll
      for (int j = 0; j < 8; ++j) zf[kc][j] = bf2f((unsigned short)z8[j]);
    }
    float lg[10];
#pragma unroll 2
    for (int r = 0; r < 10; ++r) {
      float part = 0.f;
#pragma unroll
      for (int kc = 0; kc < 4; ++kc) {
        const bf16x8 rf = *(const bf16x8*)(reb + r * 128 + kc * 32);
#pragma unroll
        for (int j = 0; j < 8; ++j) part += bf2f((unsigned short)rf[j]) * zf[kc][j];
      }
      part += __shfl_xor(part, 16);
      part += __shfl_xor(part, 32);
      lg[r] = part * 0.125f;
    }
    float mx = lg[0];
#pragma unroll
    for (int r = 1; r < 10; ++r) mx = fmaxf(mx, lg[r]);
    float ssum = 0.f;
#pragma unroll
    for (int r = 0; r < 10; ++r) { lg[r] = __expf(lg[r] - mx); ssum += lg[r]; }
    const float inv = 1.f / ssum;
#pragma unroll
    for (int r = 0; r < 10; ++r) lg[r] *= inv;
    float wsacc[4][8] = {};
#pragma unroll 2
    for (int r = 0; r < 10; ++r) {
#pragma unroll
      for (int kc = 0; kc < 4; ++kc) {
        const bf16x8 rf = *(const bf16x8*)(reb + r * 128 + kc * 32);
#pragma unroll
        for (int j = 0; j < 8; ++j)
          wsacc[kc][j] += lg[r] * bf2f((unsigned short)rf[j]);
      }
    }
    bf16x8 wf[4];
#pragma unroll
    for (int kc = 0; kc < 4; ++kc)
#pragma unroll
      for (int j = 0; j < 8; ++j) wf[kc][j] = (short)f2bf(wsacc[kc][j]);
    f32x4 oa[4] = {fz, fz, fz, fz};
#pragma unroll
    for (int kc = 0; kc < 4; ++kc)
#pragma unroll
      for (int n = 0; n < 4; ++n) oa[n] = MFMA(wf[kc], loadBc(WBv, kc * 4 + n, lane), oa[n]);
#pragma unroll
    for (int n = 0; n < 4; ++n) {
      const float bvv = bias_s[256 + l * 64 + lr + 16 * n];
#pragma unroll
      for (int i = 0; i < 4; ++i) pcur[n][i] = qa[n][i] + oa[n][i] + bvv;
    }
#pragma unroll
    for (int n = 0; n < 4; ++n)
#pragma unroll
      for (int i = 0; i < 4; ++i)
        bwrite(pep_s, quad * 4 + i, lr + 16 * n, f2bf(pcur[n][i]));
  }

  {
    float s[4], sq[4];
#pragma unroll
    for (int i = 0; i < 4; ++i) {
      s[i] = pcur[0][i] + pcur[1][i] + pcur[2][i] + pcur[3][i];
      sq[i] = pcur[0][i] * pcur[0][i] + pcur[1][i] * pcur[1][i] +
              pcur[2][i] * pcur[2][i] + pcur[3][i] * pcur[3][i];
    }
#pragma unroll
    for (int msk = 1; msk < 16; msk <<= 1) {
#pragma unroll
      for (int i = 0; i < 4; ++i) {
        s[i] += __shfl_xor(s[i], msk);
        sq[i] += __shfl_xor(sq[i], msk);
      }
    }
    float gv[4], bv2[4];
#pragma unroll
    for (int n = 0; n < 4; ++n) { gv[n] = pool_g[lr + 16 * n]; bv2[n] = pool_b[lr + 16 * n]; }
    f32x4 d[4];
#pragma unroll
    for (int i = 0; i < 4; ++i) {
      const float mean = s[i] * (1.f / 64.f);
      const float var = sq[i] * (1.f / 64.f) - mean * mean;
      const float rstd = rsqrtf(var + 1e-5f);
#pragma unroll
      for (int n = 0; n < 4; ++n) d[n][i] = (pcur[n][i] - mean) * rstd * gv[n] + bv2[n];
    }
    float* zf32 = (float*)zs;
#pragma unroll
    for (int n = 0; n < 4; ++n)
#pragma unroll
      for (int i = 0; i < 4; ++i)
        zf32[(quad * 4 + i) * 64 + lr + 16 * n] = d[n][i];
#pragma unroll
    for (int i = 0; i < 4; ++i) {
      const float4 v = *(const float4*)(&zf32[i * 256 + lane * 4]);
      *(float4*)(dbuf + (size_t)pbase * 64 + i * 256 + lane * 4) = v;
    }
#pragma unroll
    for (int n = 0; n < 4; ++n)
#pragma unroll
      for (int i = 0; i < 4; ++i)
        bwrite(q_s, quad * 4 + i, lr + 16 * n, f2bf(d[n][i]));
    const bf16x8 ad0 = bfrag(q_s, 0), ad1 = bfrag(q_s, 1);
    f32x4 h0[4] = {fz, fz, fz, fz};
#pragma unroll
    for (int n = 0; n < 4; ++n) {
      h0[n] = MFMA(ad0, loadBc(WB + WB_W0_OFF, n, lane), h0[n]);
      h0[n] = MFMA(ad1, loadBc(WB + WB_W0_OFF, 4 + n, lane), h0[n]);
    }
#pragma unroll
    for (int n = 0; n < 4; ++n)
#pragma unroll
      for (int i = 0; i < 4; ++i)
        bwrite(q_s, quad * 4 + i, lr + 16 * n, f2bf(tanhf_fast(h0[n][i])));
    const bf16x8 ah00 = bfrag(q_s, 0), ah01 = bfrag(q_s, 1);
    f32x4 h1[2] = {fz, fz};
#pragma unroll
    for (int n = 0; n < 2; ++n) {
      h1[n] = MFMA(ah00, loadBc(WB + WB_W1_OFF, n, lane), h1[n]);
      h1[n] = MFMA(ah01, loadBc(WB + WB_W1_OFF, 2 + n, lane), h1[n]);
    }
#pragma unroll
    for (int n = 0; n < 2; ++n)
#pragma unroll
      for (int i = 0; i < 4; ++i)
        bwrite(q_s, quad * 4 + i, lr + 16 * n, f2bf(tanhf_fast(h1[n][i])));
    const bf16x8 ah1 = bfrag(q_s, 0);
    f32x4 lac = MFMA(ah1, loadBc(WB + WB_W2_OFF, 0, lane), fz);
    const int b = pbase >> 11, sx0 = pbase & 2047;
#pragma unroll
    for (int i = 0; i < 4; ++i)
      logitsT[(size_t)(b * 16 + lr) * 2048 + sx0 + quad * 4 + i] = lac[i];
  }
}

// ---------------- pool2: 256 blocks, redundant softmax stats + partials ----------------
__global__ __launch_bounds__(256) void k_pool2(
    const float* __restrict__ logitsT, const float* __restrict__ dbuf,
    float* __restrict__ attp) {
  __shared__ float sh[2048];
  __shared__ float red[8];
  __shared__ float part[16][64];
  const int blk = blockIdx.x;
  const int bh = blk >> 2, q = blk & 3;
  const int b = bh >> 4;
  const int tid = threadIdx.x, lane = tid & 63, wid = tid >> 6;
  const float* lrow = logitsT + (size_t)bh * 2048;

  float m = -1e30f;
  for (int sx = tid; sx < 2048; sx += 256) {
    float v = lrow[sx];
    sh[sx] = v;
    m = fmaxf(m, v);
  }
#pragma unroll
  for (int msk = 1; msk < 64; msk <<= 1) m = fmaxf(m, __shfl_xor(m, msk));
  if (lane == 0) red[wid] = m;
  __syncthreads();
  m = fmaxf(fmaxf(red[0], red[1]), fmaxf(red[2], red[3]));

  float s1 = 0.f;
  for (int sx = tid; sx < 2048; sx += 256) {
    float e = __expf(sh[sx] - m);
    sh[sx] = e;
    s1 += e;
  }
#pragma unroll
  for (int msk = 1; msk < 64; msk <<= 1) s1 += __shfl_xor(s1, msk);
  __syncthreads();
  if (lane == 0) red[4 + wid] = s1;
  __syncthreads();
  s1 = red[4] + red[5] + red[6] + red[7];
  const float invS1 = 1.f / s1;

  float s2 = 0.f;
  for (int sx = tid; sx < 2048; sx += 256) {
    float e2 = __expf((sh[sx] - 1.f) * invS1);
    sh[sx] = e2;
    s2 += e2;
  }
#pragma unroll
  for (int msk = 1; msk < 64; msk <<= 1) s2 += __shfl_xor(s2, msk);
  __syncthreads();
  if (lane == 0) red[wid] = s2;
  __syncthreads();
  s2 = red[0] + red[1] + red[2] + red[3];
  const float invS2 = 1.f / s2;

  const int d16 = tid & 15, sxg = tid >> 4;
  float4 a4 = {0.f, 0.f, 0.f, 0.f};
  const float* db = dbuf + (size_t)b * 2048 * 64 + d16 * 4;
#pragma unroll 4
  for (int sx = q * 512 + sxg; sx < (q + 1) * 512; sx += 16) {
    const float w = sh[sx];
    const float4 v = *(const float4*)(db + (size_t)sx * 64);
    a4.x += w * v.x; a4.y += w * v.y; a4.z += w * v.z; a4.w += w * v.w;
  }
  *(float4*)(&part[sxg][d16 * 4]) = a4;
  __syncthreads();
  if (tid < 64) {
    float s = 0.f;
#pragma unroll
    for (int g2 = 0; g2 < 16; ++g2) s += part[g2][tid];
    attp[(size_t)(bh * 4 + q) * 64 + tid] = s * invS2;
  }
}

// ---------------- final: reduce partials, mean over heads, project ----------------
__global__ __launch_bounds__(256) void k_final(
    const float* __restrict__ attp, const float* __restrict__ W,
    const float* __restrict__ bias, float* __restrict__ out) {
  __shared__ float pooled[4][64];
  const int tid = threadIdx.x;
  {
    const int b = tid >> 6, d = tid & 63;
    float s = 0.f;
#pragma unroll
    for (int hq = 0; hq < 64; ++hq) s += attp[((size_t)b * 64 + hq) * 64 + d];
    pooled[b][d] = s * (1.f / 16.f);
  }
  __syncthreads();
  if (tid < 128) {
    const int b = tid >> 5, j = tid & 31;
    float s = bias[j];
#pragma unroll
    for (int d2 = 0; d2 < 64; ++d2) s += pooled[b][d2] * W[j * 64 + d2];
    out[b * 32 + j] = s;
  }
}

extern "C" void kernel_launch(void* const* d_in, const int* in_sizes, int n_in,
                              void* d_out, int out_size, void* d_ws, size_t ws_size,
                              hipStream_t stream) {
  const float* pep_feat = (const float*)d_in[0];
  const float* rec_feat = (const float*)d_in[1];
  const float* edge_feat = (const float*)d_in[2];
  const float* W_rec_esm = (const float*)d_in[3];
  const float* W_pep_esm = (const float*)d_in[4];
  const float* W_pep_emb = (const float*)d_in[5];
  const float* W_rec_emb = (const float*)d_in[6];
  const float* W_edge_emb = (const float*)d_in[7];
  const float* pep_ln_g = (const float*)d_in[8];
  const float* pep_ln_b = (const float*)d_in[9];
  const float* rec_ln_g = (const float*)d_in[10];
  const float* rec_ln_b = (const float*)d_in[11];
  const float* ga_Wp = (const float*)d_in[12];
  const float* ga_bp = (const float*)d_in[13];
  const float* ga_Wr = (const float*)d_in[14];
  const float* ga_br = (const float*)d_in[15];
  const float* ga_Wv = (const float*)d_in[16];
  const float* ga_bv = (const float*)d_in[17];
  const float* pool_ln_g = (const float*)d_in[18];
  const float* pool_ln_b = (const float*)d_in[19];
  const float* pool_W0 = (const float*)d_in[20];
  const float* pool_W1 = (const float*)d_in[21];
  const float* pool_W2 = (const float*)d_in[22];
  const float* mlp_W = (const float*)d_in[23];
  const float* mlp_b = (const float*)d_in[24];
  float* out = (float*)d_out;
  (void)ga_br;  // softmax-invariant, algebraically dropped
  (void)ws_size; (void)in_sizes; (void)n_in; (void)out_size;

  char* ws = (char*)d_ws;
  unsigned short* WB = (unsigned short*)(ws);
  unsigned short* rec_edge = (unsigned short*)(ws + 524288);
  unsigned short* pep_bf = (unsigned short*)(ws + 21495808);
  float* dbuf = (float*)(ws + 22544384);
  float* logitsT = (float*)(ws + 24641536);
  float* attp = (float*)(ws + 25165824);

  k_pack<<<1010, 256, 0, stream>>>(W_rec_esm, W_pep_esm, W_rec_emb, W_pep_emb,
                                   W_edge_emb, ga_Wp, ga_Wr, ga_Wv,
                                   pool_W0, pool_W1, pool_W2, WB);
  k_emb<<<5632, 64, 0, stream>>>(rec_feat, edge_feat, pep_feat, WB,
                                 rec_ln_g, rec_ln_b, pep_ln_g, pep_ln_b,
                                 rec_edge, pep_bf);
  k_ga<<<512, 64, 0, stream>>>(rec_edge, pep_bf, WB, ga_bp, ga_bv,
                               pool_ln_g, pool_ln_b, dbuf, logitsT);
  k_pool2<<<256, 256, 0, stream>>>(logitsT, dbuf, attp);
  k_final<<<1, 256, 0, stream>>>(attp, mlp_W, mlp_b, out);
}

// Round 12
// 170.265 us; speedup vs baseline: 2.0178x; 1.1212x over previous
//
#include <hip/hip_runtime.h>
#include <hip/hip_bf16.h>

// FeatureExtractionModel on MI355X — round 12.
// k_emb = v3 (unchanged, best known ~95us).
// k_ga v6: 4-wave cooperative block (256 thr / 16 positions), k-dim split:
//   wave w owns k in [32w,32w+32). rec_edge frags register-cached (10 x bf16x8).
//   Exchanges via LDS (lgp / oap) with 4 barriers per layer. Pool tail: wave 0.

typedef __attribute__((ext_vector_type(8))) short bf16x8;
typedef __attribute__((ext_vector_type(4))) float f32x4;

#define MFMA(a, b, c) __builtin_amdgcn_mfma_f32_16x16x32_bf16((a), (b), (c), 0, 0, 0)

#define WB_REC_OFF   0
#define WB_PEP_OFF   83968
#define WB_EDGE_OFF  167936
#define WB_P_OFF     169984
#define WB_R_OFF     186368
#define WB_V_OFF     219136
#define WB_W0_OFF    251904
#define WB_W1_OFF    256000
#define WB_W2_OFF    258048
#define WB_TOTAL     258560

__device__ __forceinline__ unsigned short f2bf(float x) {
  __hip_bfloat16 h = __float2bfloat16(x);
  return __builtin_bit_cast(unsigned short, h);
}
__device__ __forceinline__ float bf2f(unsigned short u) {
  unsigned int t = ((unsigned int)u) << 16;
  return __builtin_bit_cast(float, t);
}
__device__ __forceinline__ bf16x8 loadBc(const unsigned short* base, int chunk, int lane) {
  return *(const bf16x8*)(base + ((size_t)chunk * 64 + lane) * 8);
}
__device__ __forceinline__ float tanhf_fast(float x) {
  float e = __expf(2.f * x);
  return 1.f - 2.f / (e + 1.f);
}
__device__ __forceinline__ int swzr(int r) {
  return (r & 1) | (((r >> 1) & 7) << 2);
}

// ---------------- pack all B-operand fragments to bf16 (inline ESM combine) ----------------
__global__ __launch_bounds__(256) void k_pack(
    const float* __restrict__ Wresm, const float* __restrict__ Wpesm,
    const float* __restrict__ Wre, const float* __restrict__ Wpe,
    const float* __restrict__ Wedge, const float* __restrict__ Wp,
    const float* __restrict__ Wr, const float* __restrict__ Wv,
    const float* __restrict__ W0, const float* __restrict__ W1,
    const float* __restrict__ W2, unsigned short* __restrict__ WB) {
  const int t = blockIdx.x * 256 + threadIdx.x;
  if (t >= WB_TOTAL) return;
  float v = 0.f;
  if (t < WB_EDGE_OFF) {
    bool isPep = (t >= WB_PEP_OFF);
    int u = isPep ? (t - WB_PEP_OFF) : t;
    int j = u & 7, lane = (u >> 3) & 63, n = (u >> 9) & 3, kc = u >> 11;
    int k = kc * 32 + ((lane >> 4) << 3) + j;
    int col = n * 16 + (lane & 15);
    if (kc < 40) {
      const float* wemb = isPep ? (Wpe + col * 91 + 27) : (Wre + col * 85 + 21);
      const float* wesm = isPep ? Wpesm : Wresm;
      float s = 0.f;
#pragma unroll 8
      for (int e = 0; e < 64; ++e) s += wemb[e] * wesm[e * 1280 + k];
      v = s;
    } else {
      int kl = k - 1280;
      if (isPep) v = (kl < 27) ? Wpe[col * 91 + kl] : 0.f;
      else       v = (kl < 21) ? Wre[col * 85 + kl] : 0.f;
    }
  } else if (t < WB_P_OFF) {
    int u = t - WB_EDGE_OFF;
    int j = u & 7, lane = (u >> 3) & 63, n = (u >> 9) & 3;
    v = Wedge[(n * 16 + (lane & 15)) * 32 + ((lane >> 4) << 3) + j];
  } else if (t < WB_R_OFF) {
    int u = t - WB_P_OFF;
    int l = u >> 12, w = u & 4095;
    int j = w & 7, lane = (w >> 3) & 63, n = (w >> 9) & 3, kc = w >> 11;
    int o = kc * 32 + ((lane >> 4) << 3) + j;
    int d = n * 16 + (lane & 15);
    v = Wp[l * 4096 + d * 64 + o];
  } else if (t < WB_V_OFF) {
    int u = t - WB_R_OFF;
    int l = u >> 13, w = u & 8191;
    int j = w & 7, lane = (w >> 3) & 63, c = (w >> 9) & 15;
    int kc = c >> 3, n = c & 7;
    int o = kc * 32 + ((lane >> 4) << 3) + j;
    int k = n * 16 + (lane & 15);
    v = Wr[l * 8192 + o * 128 + k];
  } else if (t < WB_W0_OFF) {
    int u = t - WB_V_OFF;
    int l = u >> 13, w = u & 8191;
    int j = w & 7, lane = (w >> 3) & 63, n = (w >> 9) & 3, kc = w >> 11;
    int k = kc * 32 + ((lane >> 4) << 3) + j;
    int d = n * 16 + (lane & 15);
    v = Wv[l * 8192 + d * 128 + k];
  } else if (t < WB_W1_OFF) {
    int u = t - WB_W0_OFF;
    int j = u & 7, lane = (u >> 3) & 63, c = u >> 9;
    int kc = c >> 2, n = c & 3;
    v = W0[(n * 16 + (lane & 15)) * 64 + kc * 32 + ((lane >> 4) << 3) + j];
  } else if (t < WB_W2_OFF) {
    int u = t - WB_W1_OFF;
    int j = u & 7, lane = (u >> 3) & 63, c = u >> 9;
    int kc = c >> 1, n = c & 1;
    v = W1[(n * 16 + (lane & 15)) * 64 + kc * 32 + ((lane >> 4) << 3) + j];
  } else {
    int u = t - WB_W2_OFF;
    int j = u & 7, lane = (u >> 3) & 63;
    v = W2[(lane & 15) * 32 + ((lane >> 4) << 3) + j];
  }
  WB[t] = f2bf(v);
}

// ---------------- k_emb v3: 16 rows per single-wave block (unchanged) ----------------
__global__ __launch_bounds__(64) void k_emb(
    const float* __restrict__ rec_feat, const float* __restrict__ edge_feat,
    const float* __restrict__ pep_feat, const unsigned short* __restrict__ WB,
    const float* __restrict__ rec_g, const float* __restrict__ rec_b,
    const float* __restrict__ pep_g, const float* __restrict__ pep_b,
    unsigned short* __restrict__ rec_edge, unsigned short* __restrict__ pep_out) {
  __shared__ float stg[2][16][128];
  const int bid = blockIdx.x;
  const int lane = threadIdx.x;
  const int quad = lane >> 4, lr = lane & 15;
  const bool isPep = (bid >= 5120);
  const int brow = (isPep ? bid - 5120 : bid) * 16;

  const f32x4 fz = {0.f, 0.f, 0.f, 0.f};
  f32x4 acc[4] = {fz, fz, fz, fz};

  auto frag = [&](int buf, int c) -> bf16x8 {
    const int u0 = c * 8 + quad * 2;
    const int s0 = u0 ^ swzr(lr), s1 = (u0 + 1) ^ swzr(lr);
    const float4 f0 = *(const float4*)((const char*)&stg[buf][lr][0] + s0 * 16);
    const float4 f1 = *(const float4*)((const char*)&stg[buf][lr][0] + s1 * 16);
    bf16x8 a;
#pragma unroll
    for (int j = 0; j < 4; ++j) { a[j] = (short)f2bf(f0[j]); a[4 + j] = (short)f2bf(f1[j]); }
    return a;
  };

  if (!isPep) {
    const float* base = rec_feat + (size_t)brow * 1322 + 42;
    float2 ld2[16];
    auto loadg = [&](int g) {
#pragma unroll
      for (int i = 0; i < 16; ++i)
        ld2[i] = *(const float2*)(base + (size_t)i * 1322 + g * 128 + lane * 2);
    };
    auto writeg = [&](int b) {
#pragma unroll
      for (int i = 0; i < 16; ++i) {
        const int su = (lane >> 1) ^ swzr(i);
        *(float2*)((char*)&stg[b][i][0] + su * 16 + (lane & 1) * 8) = ld2[i];
      }
    };
    loadg(0); writeg(0);
    int buf = 0;
    for (int g = 0; g < 10; ++g) {
      bf16x8 bb[16];
#pragma unroll
      for (int m = 0; m < 16; ++m) bb[m] = loadBc(WB + WB_REC_OFF, g * 16 + m, lane);
      if (g < 9) loadg(g + 1);
#pragma unroll
      for (int c = 0; c < 4; ++c) {
        const bf16x8 a = frag(buf, c);
#pragma unroll
        for (int n = 0; n < 4; ++n) acc[n] = MFMA(a, bb[c * 4 + n], acc[n]);
      }
      if (g < 9) writeg(buf ^ 1);
      buf ^= 1;
    }
    {
      const float* p = rec_feat + (size_t)(brow + lr) * 1322 + quad * 8;
      bf16x8 a;
#pragma unroll
      for (int m = 0; m < 4; ++m) {
        const float2 v = *(const float2*)(p + 2 * m);
        a[2 * m] = (short)f2bf(v.x); a[2 * m + 1] = (short)f2bf(v.y);
      }
#pragma unroll
      for (int n = 0; n < 4; ++n)
        acc[n] = MFMA(a, loadBc(WB + WB_REC_OFF, 160 + n, lane), acc[n]);
    }
  } else {
    const float* base = pep_feat + (size_t)brow * 1307 + 27;
    float ldp[32];
    auto loadg = [&](int g) {
#pragma unroll
      for (int i = 0; i < 16; ++i)
#pragma unroll
        for (int ph = 0; ph < 2; ++ph)
          ldp[i * 2 + ph] = base[(size_t)i * 1307 + g * 128 + ph * 64 + lane];
    };
    auto writeg = [&](int b) {
#pragma unroll
      for (int i = 0; i < 16; ++i)
#pragma unroll
        for (int ph = 0; ph < 2; ++ph) {
          const int su = (ph * 16 + (lane >> 2)) ^ swzr(i);
          *((float*)((char*)&stg[b][i][0] + su * 16 + (lane & 3) * 4)) = ldp[i * 2 + ph];
        }
    };
    loadg(0); writeg(0);
    int buf = 0;
    for (int g = 0; g < 10; ++g) {
      bf16x8 bb[16];
#pragma unroll
      for (int m = 0; m < 16; ++m) bb[m] = loadBc(WB + WB_PEP_OFF, g * 16 + m, lane);
      if (g < 9) loadg(g + 1);
#pragma unroll
      for (int c = 0; c < 4; ++c) {
        const bf16x8 a = frag(buf, c);
#pragma unroll
        for (int n = 0; n < 4; ++n) acc[n] = MFMA(a, bb[c * 4 + n], acc[n]);
      }
      if (g < 9) writeg(buf ^ 1);
      buf ^= 1;
    }
    {
      const float* p = pep_feat + (size_t)(brow + lr) * 1307 + quad * 8;
      bf16x8 a;
#pragma unroll
      for (int j = 0; j < 8; ++j) a[j] = (short)f2bf(p[j]);
#pragma unroll
      for (int n = 0; n < 4; ++n)
        acc[n] = MFMA(a, loadBc(WB + WB_PEP_OFF, 160 + n, lane), acc[n]);
    }
  }

  float s[4], sq[4];
#pragma unroll
  for (int i = 0; i < 4; ++i) {
    s[i] = acc[0][i] + acc[1][i] + acc[2][i] + acc[3][i];
    sq[i] = acc[0][i] * acc[0][i] + acc[1][i] * acc[1][i] +
            acc[2][i] * acc[2][i] + acc[3][i] * acc[3][i];
  }
#pragma unroll
  for (int msk = 1; msk < 16; msk <<= 1) {
#pragma unroll
    for (int i = 0; i < 4; ++i) {
      s[i] += __shfl_xor(s[i], msk);
      sq[i] += __shfl_xor(sq[i], msk);
    }
  }
  const float* gp = isPep ? pep_g : rec_g;
  const float* bp = isPep ? pep_b : rec_b;
  float gv[4], bvl[4];
#pragma unroll
  for (int n = 0; n < 4; ++n) { gv[n] = gp[lr + 16 * n]; bvl[n] = bp[lr + 16 * n]; }

  if (!isPep) {
    f32x4 acce[4] = {fz, fz, fz, fz};
    {
      const float* p = edge_feat + (size_t)(brow + lr) * 32 + quad * 8;
      const float4 f0 = *(const float4*)(p);
      const float4 f1 = *(const float4*)(p + 4);
      bf16x8 a;
#pragma unroll
      for (int j = 0; j < 4; ++j) { a[j] = (short)f2bf(f0[j]); a[4 + j] = (short)f2bf(f1[j]); }
#pragma unroll
      for (int n = 0; n < 4; ++n) acce[n] = MFMA(a, loadBc(WB + WB_EDGE_OFF, n, lane), acce[n]);
    }
#pragma unroll
    for (int i = 0; i < 4; ++i) {
      const float mean = s[i] * (1.f / 64.f);
      const float var = sq[i] * (1.f / 64.f) - mean * mean;
      const float rstd = rsqrtf(var + 1e-5f);
      unsigned short* dst = rec_edge + (size_t)(brow + quad * 4 + i) * 128;
#pragma unroll
      for (int n = 0; n < 4; ++n) {
        dst[lr + 16 * n] = f2bf((acc[n][i] - mean) * rstd * gv[n] + bvl[n]);
        dst[64 + lr + 16 * n] = f2bf(acce[n][i]);
      }
    }
  } else {
#pragma unroll
    for (int i = 0; i < 4; ++i) {
      const float mean = s[i] * (1.f / 64.f);
      const float var = sq[i] * (1.f / 64.f) - mean * mean;
      const float rstd = rsqrtf(var + 1e-5f);
      unsigned short* dst = pep_out + (size_t)(brow + quad * 4 + i) * 64;
#pragma unroll
      for (int n = 0; n < 4; ++n)
        dst[lr + 16 * n] = f2bf((acc[n][i] - mean) * rstd * gv[n] + bvl[n]);
    }
  }
}

// ---------------- k_ga v6: 4-wave cooperative, k-split, reg-cached rec_edge ----------------
__global__ __launch_bounds__(256) void k_ga(
    const unsigned short* __restrict__ rec_edge, const unsigned short* __restrict__ pep_bf,
    const unsigned short* __restrict__ WB,
    const float* __restrict__ ga_bp, const float* __restrict__ ga_bv,
    const float* __restrict__ pool_g, const float* __restrict__ pool_b,
    float* __restrict__ dbuf, float* __restrict__ logitsT) {
  __shared__ unsigned short pep_s[1024];          // [16][64] bf16 swizzled
  __shared__ unsigned short q_s[1024];            // [16][64] bf16 swizzled
  __shared__ __align__(16) unsigned short zs[2048];  // [16][128] bf16 swz; also f32[1024] scratch
  __shared__ float bias_s[512];
  __shared__ float lgp[4][10][17];                // logits partials
  __shared__ float redp[4][2][16];                // LN partials
  __shared__ float oap[4][16][68];                // oa partials (padded)

  const int tid = threadIdx.x;
  const int w = tid >> 6;
  const int lane = tid & 63;
  const int quad = lane >> 4, lr = lane & 15;
  const int swz = lr & 7;
  const int pbase = blockIdx.x * 16;
  const int mycol = lr + 16 * w;
  const f32x4 fz = {0.f, 0.f, 0.f, 0.f};

  // staging (cooperative)
  bias_s[tid] = ga_bp[tid & 255];
  bias_s[256 + tid] = ga_bv[tid & 255];
  if (tid < 128) {
    const int p = tid >> 3, gg = tid & 7;
    const bf16x8 v = *(const bf16x8*)(pep_bf + (size_t)(pbase + p) * 64 + gg * 8);
    *(bf16x8*)(pep_s + p * 64 + ((gg ^ (p & 7)) << 3)) = v;
  }
  // layer-invariant rec_edge fragments for this wave's k-slice: 10 x bf16x8 (40 VGPR)
  const unsigned short* reb =
      rec_edge + (size_t)(pbase + lr) * 1280 + w * 32 + quad * 8;
  bf16x8 rfs[10];
#pragma unroll
  for (int r = 0; r < 10; ++r) rfs[r] = *(const bf16x8*)(reb + r * 128);
  __syncthreads();

  auto bwrite = [&](unsigned short* buf, int p, int col, unsigned short val) {
    buf[p * 64 + ((((col >> 3)) ^ (p & 7)) << 3) + (col & 7)] = val;
  };
  auto bfrag = [&](const unsigned short* buf, int kc) -> bf16x8 {
    return *(const bf16x8*)(buf + lr * 64 + ((((kc << 2) + quad) ^ swz) << 3));
  };

  f32x4 pcur;  // this wave's col-slice of final pep (col mycol, rows quad*4+i)
  for (int l = 0; l < 4; ++l) {
    const unsigned short* WBp = WB + WB_P_OFF + l * 4096;
    const unsigned short* WBr = WB + WB_R_OFF + l * 8192;
    const unsigned short* WBv = WB + WB_V_OFF + l * 8192;

    // q slice (n = w)
    f32x4 qa = fz;
    qa = MFMA(bfrag(pep_s, 0), loadBc(WBp, w, lane), qa);
    qa = MFMA(bfrag(pep_s, 1), loadBc(WBp, 4 + w, lane), qa);
    const float bpv = bias_s[l * 64 + mycol];
#pragma unroll
    for (int i = 0; i < 4; ++i) qa[i] += bpv;
#pragma unroll
    for (int i = 0; i < 4; ++i) bwrite(q_s, quad * 4 + i, mycol, f2bf(qa[i]));
    __syncthreads();  // #1: q_s complete

    const bf16x8 aq0 = bfrag(q_s, 0), aq1 = bfrag(q_s, 1);
    // z slice: n = 2w, 2w+1  (k in [32w, 32w+32))
    f32x4 za0 = fz, za1 = fz;
    za0 = MFMA(aq0, loadBc(WBr, 2 * w, lane), za0);
    za0 = MFMA(aq1, loadBc(WBr, 8 + 2 * w, lane), za0);
    za1 = MFMA(aq0, loadBc(WBr, 2 * w + 1, lane), za1);
    za1 = MFMA(aq1, loadBc(WBr, 9 + 2 * w, lane), za1);
#pragma unroll
    for (int i = 0; i < 4; ++i) {
      const int p = quad * 4 + i;
      const int k0 = 16 * (2 * w) + lr, k1 = 16 * (2 * w + 1) + lr;
      zs[p * 128 + ((((k0 >> 3) ^ (p & 7)) << 3) | (k0 & 7))] = f2bf(za0[i]);
      zs[p * 128 + ((((k1 >> 3) ^ (p & 7)) << 3) | (k1 & 7))] = f2bf(za1[i]);
    }
    // own zf slice (written by own wave; intra-wave lgkmcnt ordering)
    float zfw[8];
    {
      const bf16x8 z8 = *(const bf16x8*)(zs + lr * 128 + (((quad + 4 * w) ^ swz) << 3));
#pragma unroll
      for (int j = 0; j < 8; ++j) zfw[j] = bf2f((unsigned short)z8[j]);
    }
    // logits partial over own 32-k slice
#pragma unroll
    for (int r = 0; r < 10; ++r) {
      float part = 0.f;
#pragma unroll
      for (int j = 0; j < 8; ++j) part += bf2f((unsigned short)rfs[r][j]) * zfw[j];
      part += __shfl_xor(part, 16);
      part += __shfl_xor(part, 32);
      if (quad == 0) lgp[w][r][lr] = part;
    }
    __syncthreads();  // #2: lgp complete
    float lg[10];
#pragma unroll
    for (int r = 0; r < 10; ++r)
      lg[r] = (lgp[0][r][lr] + lgp[1][r][lr] + lgp[2][r][lr] + lgp[3][r][lr]) * 0.125f;
    float mx = lg[0];
#pragma unroll
    for (int r = 1; r < 10; ++r) mx = fmaxf(mx, lg[r]);
    float ssum = 0.f;
#pragma unroll
    for (int r = 0; r < 10; ++r) { lg[r] = __expf(lg[r] - mx); ssum += lg[r]; }
    const float inv = 1.f / ssum;
#pragma unroll
    for (int r = 0; r < 10; ++r) lg[r] *= inv;
    // ws over own k slice
    float wsacc[8] = {};
#pragma unroll
    for (int r = 0; r < 10; ++r)
#pragma unroll
      for (int j = 0; j < 8; ++j)
        wsacc[j] += lg[r] * bf2f((unsigned short)rfs[r][j]);
    bf16x8 wf;
#pragma unroll
    for (int j = 0; j < 8; ++j) wf[j] = (short)f2bf(wsacc[j]);
    // oa partial: own kc = w, all n
    f32x4 oa[4];
#pragma unroll
    for (int n = 0; n < 4; ++n) oa[n] = MFMA(wf, loadBc(WBv, w * 4 + n, lane), fz);
#pragma unroll
    for (int n = 0; n < 4; ++n)
#pragma unroll
      for (int i = 0; i < 4; ++i)
        oap[w][quad * 4 + i][n * 16 + lr] = oa[n][i];
    __syncthreads();  // #3: oap complete
    const float bvv = bias_s[256 + l * 64 + mycol];
#pragma unroll
    for (int i = 0; i < 4; ++i) {
      const int p = quad * 4 + i;
      const float o = oap[0][p][mycol] + oap[1][p][mycol] +
                      oap[2][p][mycol] + oap[3][p][mycol];
      pcur[i] = qa[i] + o + bvv;
    }
#pragma unroll
    for (int i = 0; i < 4; ++i) bwrite(pep_s, quad * 4 + i, mycol, f2bf(pcur[i]));
    __syncthreads();  // #4: pep_s ready for next layer
  }

  // ---- pooling: LN (cooperative) ----
  {
    float s[4], sq[4];
#pragma unroll
    for (int i = 0; i < 4; ++i) { s[i] = pcur[i]; sq[i] = pcur[i] * pcur[i]; }
#pragma unroll
    for (int msk = 1; msk < 16; msk <<= 1) {
#pragma unroll
      for (int i = 0; i < 4; ++i) {
        s[i] += __shfl_xor(s[i], msk);
        sq[i] += __shfl_xor(sq[i], msk);
      }
    }
    if (lr == 0) {
#pragma unroll
      for (int i = 0; i < 4; ++i) {
        redp[w][0][quad * 4 + i] = s[i];
        redp[w][1][quad * 4 + i] = sq[i];
      }
    }
    __syncthreads();  // #5: redp complete
    const float gv = pool_g[mycol], bv2 = pool_b[mycol];
    float d[4];
    float* zf32 = (float*)zs;
#pragma unroll
    for (int i = 0; i < 4; ++i) {
      const int p = quad * 4 + i;
      const float sf = redp[0][0][p] + redp[1][0][p] + redp[2][0][p] + redp[3][0][p];
      const float sqf = redp[0][1][p] + redp[1][1][p] + redp[2][1][p] + redp[3][1][p];
      const float mean = sf * (1.f / 64.f);
      const float var = sqf * (1.f / 64.f) - mean * mean;
      const float rstd = rsqrtf(var + 1e-5f);
      d[i] = (pcur[i] - mean) * rstd * gv + bv2;
      zf32[p * 64 + mycol] = d[i];
      bwrite(q_s, p, mycol, f2bf(d[i]));
    }
    __syncthreads();  // #6: zf32 + q_s(d) complete
    {  // dbuf: [16 pos][64] f32 coalesced, all 256 threads
      const float4 v = *(const float4*)(&zf32[tid * 4]);
      *(float4*)(dbuf + (size_t)pbase * 64 + tid * 4) = v;
    }
    // tiny MLP tail: wave 0 only (single-wave semantics)
    if (w == 0) {
      const bf16x8 ad0 = bfrag(q_s, 0), ad1 = bfrag(q_s, 1);
      f32x4 h0[4] = {fz, fz, fz, fz};
#pragma unroll
      for (int n = 0; n < 4; ++n) {
        h0[n] = MFMA(ad0, loadBc(WB + WB_W0_OFF, n, lane), h0[n]);
        h0[n] = MFMA(ad1, loadBc(WB + WB_W0_OFF, 4 + n, lane), h0[n]);
      }
#pragma unroll
      for (int n = 0; n < 4; ++n)
#pragma unroll
        for (int i = 0; i < 4; ++i)
          bwrite(q_s, quad * 4 + i, lr + 16 * n, f2bf(tanhf_fast(h0[n][i])));
      const bf16x8 ah00 = bfrag(q_s, 0), ah01 = bfrag(q_s, 1);
      f32x4 h1[2] = {fz, fz};
#pragma unroll
      for (int n = 0; n < 2; ++n) {
        h1[n] = MFMA(ah00, loadBc(WB + WB_W1_OFF, n, lane), h1[n]);
        h1[n] = MFMA(ah01, loadBc(WB + WB_W1_OFF, 2 + n, lane), h1[n]);
      }
#pragma unroll
      for (int n = 0; n < 2; ++n)
#pragma unroll
        for (int i = 0; i < 4; ++i)
          bwrite(q_s, quad * 4 + i, lr + 16 * n, f2bf(tanhf_fast(h1[n][i])));
      const bf16x8 ah1 = bfrag(q_s, 0);
      f32x4 lac = MFMA(ah1, loadBc(WB + WB_W2_OFF, 0, lane), fz);
      const int b = pbase >> 11, sx0 = pbase & 2047;
#pragma unroll
      for (int i = 0; i < 4; ++i)
        logitsT[(size_t)(b * 16 + lr) * 2048 + sx0 + quad * 4 + i] = lac[i];
    }
  }
}

// ---------------- pool2: 256 blocks, redundant softmax stats + partials ----------------
__global__ __launch_bounds__(256) void k_pool2(
    const float* __restrict__ logitsT, const float* __restrict__ dbuf,
    float* __restrict__ attp) {
  __shared__ float sh[2048];
  __shared__ float red[8];
  __shared__ float part[16][64];
  const int blk = blockIdx.x;
  const int bh = blk >> 2, q = blk & 3;
  const int b = bh >> 4;
  const int tid = threadIdx.x, lane = tid & 63, wid = tid >> 6;
  const float* lrow = logitsT + (size_t)bh * 2048;

  float m = -1e30f;
  for (int sx = tid; sx < 2048; sx += 256) {
    float v = lrow[sx];
    sh[sx] = v;
    m = fmaxf(m, v);
  }
#pragma unroll
  for (int msk = 1; msk < 64; msk <<= 1) m = fmaxf(m, __shfl_xor(m, msk));
  if (lane == 0) red[wid] = m;
  __syncthreads();
  m = fmaxf(fmaxf(red[0], red[1]), fmaxf(red[2], red[3]));

  float s1 = 0.f;
  for (int sx = tid; sx < 2048; sx += 256) {
    float e = __expf(sh[sx] - m);
    sh[sx] = e;
    s1 += e;
  }
#pragma unroll
  for (int msk = 1; msk < 64; msk <<= 1) s1 += __shfl_xor(s1, msk);
  __syncthreads();
  if (lane == 0) red[4 + wid] = s1;
  __syncthreads();
  s1 = red[4] + red[5] + red[6] + red[7];
  const float invS1 = 1.f / s1;

  float s2 = 0.f;
  for (int sx = tid; sx < 2048; sx += 256) {
    float e2 = __expf((sh[sx] - 1.f) * invS1);
    sh[sx] = e2;
    s2 += e2;
  }
#pragma unroll
  for (int msk = 1; msk < 64; msk <<= 1) s2 += __shfl_xor(s2, msk);
  __syncthreads();
  if (lane == 0) red[wid] = s2;
  __syncthreads();
  s2 = red[0] + red[1] + red[2] + red[3];
  const float invS2 = 1.f / s2;

  const int d16 = tid & 15, sxg = tid >> 4;
  float4 a4 = {0.f, 0.f, 0.f, 0.f};
  const float* db = dbuf + (size_t)b * 2048 * 64 + d16 * 4;
#pragma unroll 4
  for (int sx = q * 512 + sxg; sx < (q + 1) * 512; sx += 16) {
    const float w = sh[sx];
    const float4 v = *(const float4*)(db + (size_t)sx * 64);
    a4.x += w * v.x; a4.y += w * v.y; a4.z += w * v.z; a4.w += w * v.w;
  }
  *(float4*)(&part[sxg][d16 * 4]) = a4;
  __syncthreads();
  if (tid < 64) {
    float s = 0.f;
#pragma unroll
    for (int g2 = 0; g2 < 16; ++g2) s += part[g2][tid];
    attp[(size_t)(bh * 4 + q) * 64 + tid] = s * invS2;
  }
}

// ---------------- final: reduce partials, mean over heads, project ----------------
__global__ __launch_bounds__(256) void k_final(
    const float* __restrict__ attp, const float* __restrict__ W,
    const float* __restrict__ bias, float* __restrict__ out) {
  __shared__ float pooled[4][64];
  const int tid = threadIdx.x;
  {
    const int b = tid >> 6, d = tid & 63;
    float s = 0.f;
#pragma unroll
    for (int hq = 0; hq < 64; ++hq) s += attp[((size_t)b * 64 + hq) * 64 + d];
    pooled[b][d] = s * (1.f / 16.f);
  }
  __syncthreads();
  if (tid < 128) {
    const int b = tid >> 5, j = tid & 31;
    float s = bias[j];
#pragma unroll
    for (int d2 = 0; d2 < 64; ++d2) s += pooled[b][d2] * W[j * 64 + d2];
    out[b * 32 + j] = s;
  }
}

extern "C" void kernel_launch(void* const* d_in, const int* in_sizes, int n_in,
                              void* d_out, int out_size, void* d_ws, size_t ws_size,
                              hipStream_t stream) {
  const float* pep_feat = (const float*)d_in[0];
  const float* rec_feat = (const float*)d_in[1];
  const float* edge_feat = (const float*)d_in[2];
  const float* W_rec_esm = (const float*)d_in[3];
  const float* W_pep_esm = (const float*)d_in[4];
  const float* W_pep_emb = (const float*)d_in[5];
  const float* W_rec_emb = (const float*)d_in[6];
  const float* W_edge_emb = (const float*)d_in[7];
  const float* pep_ln_g = (const float*)d_in[8];
  const float* pep_ln_b = (const float*)d_in[9];
  const float* rec_ln_g = (const float*)d_in[10];
  const float* rec_ln_b = (const float*)d_in[11];
  const float* ga_Wp = (const float*)d_in[12];
  const float* ga_bp = (const float*)d_in[13];
  const float* ga_Wr = (const float*)d_in[14];
  const float* ga_br = (const float*)d_in[15];
  const float* ga_Wv = (const float*)d_in[16];
  const float* ga_bv = (const float*)d_in[17];
  const float* pool_ln_g = (const float*)d_in[18];
  const float* pool_ln_b = (const float*)d_in[19];
  const float* pool_W0 = (const float*)d_in[20];
  const float* pool_W1 = (const float*)d_in[21];
  const float* pool_W2 = (const float*)d_in[22];
  const float* mlp_W = (const float*)d_in[23];
  const float* mlp_b = (const float*)d_in[24];
  float* out = (float*)d_out;
  (void)ga_br;  // softmax-invariant, algebraically dropped
  (void)ws_size; (void)in_sizes; (void)n_in; (void)out_size;

  char* ws = (char*)d_ws;
  unsigned short* WB = (unsigned short*)(ws);
  unsigned short* rec_edge = (unsigned short*)(ws + 524288);
  unsigned short* pep_bf = (unsigned short*)(ws + 21495808);
  float* dbuf = (float*)(ws + 22544384);
  float* logitsT = (float*)(ws + 24641536);
  float* attp = (float*)(ws + 25165824);

  k_pack<<<1010, 256, 0, stream>>>(W_rec_esm, W_pep_esm, W_rec_emb, W_pep_emb,
                                   W_edge_emb, ga_Wp, ga_Wr, ga_Wv,
                                   pool_W0, pool_W1, pool_W2, WB);
  k_emb<<<5632, 64, 0, stream>>>(rec_feat, edge_feat, pep_feat, WB,
                                 rec_ln_g, rec_ln_b, pep_ln_g, pep_ln_b,
                                 rec_edge, pep_bf);
  k_ga<<<512, 256, 0, stream>>>(rec_edge, pep_bf, WB, ga_bp, ga_bv,
                                pool_ln_g, pool_ln_b, dbuf, logitsT);
  k_pool2<<<256, 256, 0, stream>>>(logitsT, dbuf, attp);
  k_final<<<1, 256, 0, stream>>>(attp, mlp_W, mlp_b, out);
}